// Round 16
// baseline (403.204 us; speedup 1.0000x reference)
//
#include <hip/hip_runtime.h>
#include <hip/hip_bf16.h>
#include <math.h>
#include <stdint.h>

#define LRA 0.2f

typedef __attribute__((ext_vector_type(8))) short bf16x8;
typedef __attribute__((ext_vector_type(8))) unsigned short u16x8;
typedef __attribute__((ext_vector_type(4))) float f32x4;
typedef unsigned long long u64;

__device__ __forceinline__ unsigned short f2bf(float v) {
  union { __hip_bfloat16 b; unsigned short u; } c;
  c.b = __float2bfloat16(v);
  return c.u;
}
__device__ __forceinline__ float bf2f(unsigned short h) {
  union { float f; unsigned int u; } a; a.u = ((unsigned int)h) << 16;
  return a.f;
}
__device__ __forceinline__ float warp_sum(float v){
  #pragma unroll
  for (int s = 32; s; s >>= 1) v += __shfl_xor(v, s);
  return v;
}

// =============== adjacency -> bitmasks (once) ===============
__global__ __launch_bounds__(256) void k_mask(const int* __restrict__ adj, u64* __restrict__ mg){
  const int t = threadIdx.x, lane = t & 63, w = t >> 6, b = blockIdx.x;
  const int* adjb = adj + (size_t)b * 128 * 128;
  for (int i = w * 32; i < w * 32 + 32; ++i) {
    u64 b0 = __ballot(adjb[i * 128 + lane] > 0);
    u64 b1 = __ballot(adjb[i * 128 + 64 + lane] > 0);
    if (lane == 0) { mg[((size_t)b * 128 + i) * 2] = b0; mg[((size_t)b * 128 + i) * 2 + 1] = b1; }
  }
}

// =============== prep: W_heads -> fragment-layout hi/lo ===============
__global__ __launch_bounds__(64) void k_prep1(
    const float* __restrict__ Whw, unsigned short* __restrict__ BH, unsigned short* __restrict__ BL)
{
  const int kt = blockIdx.x, nt = blockIdx.y, l = threadIdx.x;
  const int n = nt * 16 + (l & 15), k0 = kt * 32 + (l >> 4) * 8;
  const int hd = n / 60, j = n - hd * 60;
  uint4 hv, lv;
  unsigned int* hp = (unsigned int*)&hv;
  unsigned int* lp = (unsigned int*)&lv;
  #pragma unroll
  for (int p = 0; p < 4; ++p) {
    unsigned short hh[2], ll[2];
    #pragma unroll
    for (int e = 0; e < 2; ++e) {
      const int k = k0 + p * 2 + e;
      const float v = (n < 480 && k < 133) ? Whw[((size_t)hd * 133 + k) * 60 + j] : 0.f;
      const unsigned short h = f2bf(v);
      hh[e] = h; ll[e] = f2bf(v - bf2f(h));
    }
    hp[p] = hh[0] | ((unsigned int)hh[1] << 16);
    lp[p] = ll[0] | ((unsigned int)ll[1] << 16);
  }
  const size_t off = (((size_t)(kt * 32 + nt)) * 64 + l) * 8;
  *(uint4*)&BH[off] = hv;
  *(uint4*)&BL[off] = lv;
}

// =============== prep: Wout -> fragment-layout hi/lo ===============
__global__ __launch_bounds__(64) void k_prep2(
    const float* __restrict__ W, unsigned short* __restrict__ BH, unsigned short* __restrict__ BL)
{
  const int kt = blockIdx.x, nt = blockIdx.y, l = threadIdx.x;
  const int n = nt * 16 + (l & 15), k0 = kt * 32 + (l >> 4) * 8;
  uint4 hv, lv;
  unsigned int* hp = (unsigned int*)&hv;
  unsigned int* lp = (unsigned int*)&lv;
  #pragma unroll
  for (int p = 0; p < 4; ++p) {
    unsigned short hh[2], ll[2];
    #pragma unroll
    for (int e = 0; e < 2; ++e) {
      const int k = k0 + p * 2 + e;
      const float v = (n < 300 && k < 480) ? W[(size_t)k * 300 + n] : 0.f;
      const unsigned short h = f2bf(v);
      hh[e] = h; ll[e] = f2bf(v - bf2f(h));
    }
    hp[p] = hh[0] | ((unsigned int)hh[1] << 16);
    lp[p] = ll[0] | ((unsigned int)ll[1] << 16);
  }
  const size_t off = (((size_t)(kt * 20 + nt)) * 64 + l) * 8;
  *(uint4*)&BH[off] = hv;
  *(uint4*)&BL[off] = lv;
}

// =============== GEMM1: Wh = x @ Bcat; 4 row-parts per batch ===============
__global__ __launch_bounds__(512) void k_gemm1(
    const float* __restrict__ x,
    const unsigned short* __restrict__ BH, const unsigned short* __restrict__ BL,
    const float* __restrict__ asrc, const float* __restrict__ adst,
    unsigned int* __restrict__ buf1, float* __restrict__ s1g, float* __restrict__ d1g)
{
  __shared__ unsigned int Apk[32][32];
  __shared__ float asl[512], adl[512];
  __shared__ float sp0[8][32], sp1[8][32], dp0[8][32], dp1[8][32];
  const int t = threadIdx.x, lane = t & 63, w = t >> 6, r = lane & 15, g = lane >> 4;
  const int b = blockIdx.x >> 2, p = blockIdx.x & 3;
  const int row0 = p * 32;
  const float* xb = x + (size_t)b * 128 * 133;
  unsigned int* slab = buf1 + (size_t)b * 61440;

  asl[t] = (t < 480) ? asrc[t] : 0.f;
  adl[t] = (t < 480) ? adst[t] : 0.f;

  f32x4 acc[2][4];
  #pragma unroll
  for (int mt = 0; mt < 2; ++mt)
    #pragma unroll
    for (int ntl = 0; ntl < 4; ++ntl) acc[mt][ntl] = (f32x4){0.f,0.f,0.f,0.f};

  for (int kt = 0; kt < 5; ++kt) {
    if (t < 256) {
      const int row_l = t >> 3, sl = t & 7;
      const int k0 = kt * 32 + sl * 4;
      uint4 pk;
      unsigned int* pp = (unsigned int*)&pk;
      #pragma unroll
      for (int e = 0; e < 4; ++e) {
        const int k = k0 + e;
        const float v = (k < 133) ? xb[(size_t)(row0 + row_l) * 133 + k] : 0.f;
        const unsigned short h = f2bf(v);
        pp[e] = ((unsigned int)h << 16) | f2bf(v - bf2f(h));
      }
      *(uint4*)&Apk[row_l][((sl ^ (row_l & 7)) << 2)] = pk;
    }
    bf16x8 bh[4], bl[4];
    #pragma unroll
    for (int ntl = 0; ntl < 4; ++ntl) {
      const int nt = w * 4 + ntl;
      const size_t off = (((size_t)(kt * 32 + nt)) * 64 + lane) * 8;
      bh[ntl] = *(const bf16x8*)&BH[off];
      bl[ntl] = *(const bf16x8*)&BL[off];
    }
    __syncthreads();
    #pragma unroll
    for (int mt = 0; mt < 2; ++mt) {
      const int row_l = mt * 16 + r, key = r & 7;
      const uint4 p0 = *(const uint4*)&Apk[row_l][(((2*g)   ^ key) << 2)];
      const uint4 p1 = *(const uint4*)&Apk[row_l][(((2*g+1) ^ key) << 2)];
      const unsigned int pw[8] = {p0.x,p0.y,p0.z,p0.w,p1.x,p1.y,p1.z,p1.w};
      bf16x8 ah, al;
      #pragma unroll
      for (int e = 0; e < 8; ++e) { ah[e] = (short)(pw[e] >> 16); al[e] = (short)(pw[e] & 0xffffu); }
      #pragma unroll
      for (int ntl = 0; ntl < 4; ++ntl) {
        acc[mt][ntl] = __builtin_amdgcn_mfma_f32_16x16x32_bf16(ah, bh[ntl], acc[mt][ntl], 0,0,0);
        acc[mt][ntl] = __builtin_amdgcn_mfma_f32_16x16x32_bf16(al, bh[ntl], acc[mt][ntl], 0,0,0);
        acc[mt][ntl] = __builtin_amdgcn_mfma_f32_16x16x32_bf16(ah, bl[ntl], acc[mt][ntl], 0,0,0);
      }
    }
    __syncthreads();
  }
  #pragma unroll
  for (int mt = 0; mt < 2; ++mt)
    #pragma unroll
    for (int ntl = 0; ntl < 4; ++ntl) {
      const int cc = (w * 4 + ntl) * 16 + r;
      if (cc < 480) {
        const int hd = cc / 60, cl = cc - hd * 60;
        uint4 pv;
        unsigned int* pp = (unsigned int*)&pv;
        #pragma unroll
        for (int q = 0; q < 4; ++q) {
          const float v = acc[mt][ntl][q];
          const unsigned short h = f2bf(v);
          pp[q] = ((unsigned int)h << 16) | f2bf(v - bf2f(h));
        }
        *(uint4*)&slab[(size_t)hd * 7680 + (size_t)cl * 128 + row0 + mt * 16 + (g << 2)] = pv;
      }
    }
  const int thr0 = 60 - 4 * w;
  #pragma unroll
  for (int mt = 0; mt < 2; ++mt) {
    #pragma unroll
    for (int q = 0; q < 4; ++q) {
      float s0 = 0.f, s1 = 0.f, d0 = 0.f, d1 = 0.f;
      #pragma unroll
      for (int ntl = 0; ntl < 4; ++ntl) {
        const int loc = ntl * 16 + r;
        const int cc = w * 64 + loc;
        const float a = acc[mt][ntl][q];
        const float as = asl[cc], ad = adl[cc];
        if (loc < thr0) { s0 += a * as; d0 += a * ad; }
        else            { s1 += a * as; d1 += a * ad; }
      }
      #pragma unroll
      for (int s = 1; s <= 8; s <<= 1) {
        s0 += __shfl_xor(s0, s); s1 += __shfl_xor(s1, s);
        d0 += __shfl_xor(d0, s); d1 += __shfl_xor(d1, s);
      }
      if (r == 0) {
        const int row_l = mt * 16 + g * 4 + q;
        sp0[w][row_l] = s0; sp1[w][row_l] = s1;
        dp0[w][row_l] = d0; dp1[w][row_l] = d1;
      }
    }
  }
  __syncthreads();
  if (t < 256) {
    const int hd = t >> 5, row_l = t & 31;
    s1g[((size_t)b * 8 + hd) * 128 + row0 + row_l] = sp0[hd][row_l] + (hd > 0 ? sp1[hd-1][row_l] : 0.f);
    d1g[((size_t)b * 8 + hd) * 128 + row0 + row_l] = dp0[hd][row_l] + (hd > 0 ? dp1[hd-1][row_l] : 0.f);
  }
}

// ===== merged attention-fragment generator (shared by att1/att2) =====
__device__ __forceinline__ float make_att_frags(
    const float si, const u64 ma, const u64 mb2, const float* darr,
    const int g, bf16x8* pah, bf16x8* pal)
{
  const unsigned int mby[4] = {
    (unsigned int)(ma  >> (g * 8)) & 0xffu,
    (unsigned int)(ma  >> (32 + g * 8)) & 0xffu,
    (unsigned int)(mb2 >> (g * 8)) & 0xffu,
    (unsigned int)(mb2 >> (32 + g * 8)) & 0xffu };
  float ev[4][8];
  float mx = -3e38f;
  #pragma unroll
  for (int kt = 0; kt < 4; ++kt)
    #pragma unroll
    for (int e = 0; e < 8; ++e) {
      const int j = ((kt & 1) * 32) + ((kt >> 1) * 64) + g * 8 + e;
      float v = si + darr[j];
      v = fmaxf(v, LRA * v);
      const float vv = (mby[((kt & 1) << 1) | (kt >> 1)] & (1u << e)) ? v : -3e38f;
      ev[kt][e] = vv;
      mx = fmaxf(mx, vv);
    }
  mx = fmaxf(mx, __shfl_xor(mx, 16));
  mx = fmaxf(mx, __shfl_xor(mx, 32));
  float sum = 0.f;
  #pragma unroll
  for (int kt = 0; kt < 4; ++kt)
    #pragma unroll
    for (int e = 0; e < 8; ++e) {
      const float p = (ev[kt][e] > -1e37f) ? __expf(ev[kt][e] - mx) : 0.f;
      ev[kt][e] = p;
      sum += p;
    }
  sum += __shfl_xor(sum, 16);
  sum += __shfl_xor(sum, 32);
  #pragma unroll
  for (int kt = 0; kt < 4; ++kt) {
    const int ks = ((kt & 1) << 1) | (kt >> 1);
    union { unsigned int u[4]; bf16x8 v; } hw, lw;
    #pragma unroll
    for (int p2 = 0; p2 < 4; ++p2) {
      const float p0 = ev[ks][2 * p2], p1 = ev[ks][2 * p2 + 1];
      const unsigned short h0 = f2bf(p0), h1 = f2bf(p1);
      hw.u[p2] = h0 | ((unsigned int)h1 << 16);
      lw.u[p2] = f2bf(p0 - bf2f(h0)) | ((unsigned int)f2bf(p1 - bf2f(h1)) << 16);
    }
    pah[kt] = hw.v;
    pal[kt] = lw.v;
  }
  return 1.f / sum;
}

// =============== att1: per (b,head); h = elu(att@Wh) in-place ===============
__global__ __launch_bounds__(256) void k_att1(
    unsigned int* __restrict__ buf1, const u64* __restrict__ mg,
    const float* __restrict__ s1g, const float* __restrict__ d1g)
{
  __shared__ unsigned short Th[16][64][8], Tl[16][64][8];
  __shared__ float sarr[128], darr[128];
  __shared__ u64 mAr[128], mBr[128];
  const int t = threadIdx.x, lane = t & 63, w = t >> 6, r = lane & 15, g = lane >> 4;
  const int bid = blockIdx.x;
  const int lb = ((bid & 7) << 9) | (bid >> 3);
  const int b = lb >> 3, hd = lb & 7;
  const size_t sl = (size_t)b * 8 + hd;
  unsigned int* slab = buf1 + sl * 7680;

  if (t < 128) {
    sarr[t] = s1g[sl * 128 + t];
    darr[t] = d1g[sl * 128 + t];
    mAr[t] = mg[((size_t)b * 128 + t) * 2];
    mBr[t] = mg[((size_t)b * 128 + t) * 2 + 1];
  }
  #pragma unroll
  for (int ii = 0; ii < 4; ++ii) {
    const int idx = t + ii * 256;
    const int c = idx & 63, jg = idx >> 6;
    uint4 p0 = {0,0,0,0}, p1 = {0,0,0,0};
    if (c < 60) {
      const uint4* src = (const uint4*)&slab[(size_t)c * 128 + jg * 8];
      p0 = src[0]; p1 = src[1];
    }
    const unsigned int pw[8] = {p0.x,p0.y,p0.z,p0.w,p1.x,p1.y,p1.z,p1.w};
    u16x8 hv, lv;
    #pragma unroll
    for (int e = 0; e < 8; ++e) { hv[e] = (unsigned short)(pw[e] >> 16); lv[e] = (unsigned short)(pw[e] & 0xffffu); }
    const int tile = ((c >> 4) << 2) | (jg >> 2);
    const int li = ((jg & 3) << 4) | (c & 15);
    *(u16x8*)&Th[tile][li][0] = hv;
    *(u16x8*)&Tl[tile][li][0] = lv;
  }
  __syncthreads();
  bf16x8 pah[2][4], pal[2][4];
  float inv2[2];
  #pragma unroll
  for (int mt = 0; mt < 2; ++mt) {
    const int i = w * 32 + mt * 16 + r;
    inv2[mt] = make_att_frags(sarr[i], mAr[i], mBr[i], darr, g, pah[mt], pal[mt]);
  }
  f32x4 acc[2][4];
  #pragma unroll
  for (int mt = 0; mt < 2; ++mt)
    #pragma unroll
    for (int nt = 0; nt < 4; ++nt) acc[mt][nt] = (f32x4){0.f,0.f,0.f,0.f};
  #pragma unroll
  for (int kt = 0; kt < 4; ++kt)
    #pragma unroll
    for (int nt = 0; nt < 4; ++nt) {
      const bf16x8 bh = *(const bf16x8*)&Th[(nt << 2) | kt][lane][0];
      const bf16x8 bl = *(const bf16x8*)&Tl[(nt << 2) | kt][lane][0];
      #pragma unroll
      for (int mt = 0; mt < 2; ++mt) {
        acc[mt][nt] = __builtin_amdgcn_mfma_f32_16x16x32_bf16(pah[mt][kt], bh, acc[mt][nt], 0,0,0);
        acc[mt][nt] = __builtin_amdgcn_mfma_f32_16x16x32_bf16(pal[mt][kt], bh, acc[mt][nt], 0,0,0);
        acc[mt][nt] = __builtin_amdgcn_mfma_f32_16x16x32_bf16(pah[mt][kt], bl, acc[mt][nt], 0,0,0);
      }
    }
  #pragma unroll
  for (int mt = 0; mt < 2; ++mt) {
    float sc[4];
    #pragma unroll
    for (int q = 0; q < 4; ++q) sc[q] = __shfl(inv2[mt], g * 4 + q);
    #pragma unroll
    for (int nt = 0; nt < 4; ++nt) {
      const int cc = nt * 16 + r;
      if (cc < 60) {
        #pragma unroll
        for (int q = 0; q < 4; ++q) {
          const int row = w * 32 + mt * 16 + g * 4 + q;
          float v = acc[mt][nt][q] * sc[q];
          v = v > 0.f ? v : __expf(v) - 1.f;
          const unsigned short h = f2bf(v), l = f2bf(v - bf2f(h));
          slab[(size_t)row * 60 + cc] = ((unsigned int)h << 16) | l;
        }
      }
    }
  }
}

// =============== GEMM2: Wo = h @ W_out; 2 row-parts (64 rows) per batch ===============
__global__ __launch_bounds__(256, 3) void k_gemm2(
    unsigned int* __restrict__ buf1,
    const unsigned short* __restrict__ BH, const unsigned short* __restrict__ BL,
    const float* __restrict__ aos, const float* __restrict__ aod,
    float* __restrict__ s2g, float* __restrict__ d2g)
{
  __shared__ unsigned int Apk[64][32];
  __shared__ float aosl[320], aodl[320];
  __shared__ float sred[4][64], dred[4][64];
  const int t = threadIdx.x, lane = t & 63, w = t >> 6, r = lane & 15, g = lane >> 4;
  const int b = blockIdx.x >> 1, p = blockIdx.x & 1;
  const int row0 = p * 64;
  unsigned int* slab = buf1 + (size_t)b * 61440;
  if (t < 320) { aosl[t] = t < 300 ? aos[t] : 0.f; aodl[t] = t < 300 ? aod[t] : 0.f; }

  f32x4 acc[4][5];
  #pragma unroll
  for (int mt = 0; mt < 4; ++mt)
    #pragma unroll
    for (int ntl = 0; ntl < 5; ++ntl) acc[mt][ntl] = (f32x4){0.f,0.f,0.f,0.f};

  for (int kt = 0; kt < 15; ++kt) {
    #pragma unroll
    for (int i = 0; i < 2; ++i) {
      const int idx = t + i * 256, row_l = idx >> 3, sl = idx & 7;
      const int k0 = kt * 32 + sl * 4;
      const int hd = k0 / 60, c = k0 - hd * 60;
      const uint4 v = *(const uint4*)&slab[(size_t)hd * 7680 + (size_t)(row0 + row_l) * 60 + c];
      *(uint4*)&Apk[row_l][((sl ^ (row_l & 7)) << 2)] = v;
    }
    bf16x8 bh[5], bl[5];
    #pragma unroll
    for (int ntl = 0; ntl < 5; ++ntl) {
      const int nt = w * 5 + ntl;
      const size_t off = (((size_t)(kt * 20 + nt)) * 64 + lane) * 8;
      bh[ntl] = *(const bf16x8*)&BH[off];
      bl[ntl] = *(const bf16x8*)&BL[off];
    }
    __syncthreads();
    #pragma unroll
    for (int mt = 0; mt < 4; ++mt) {
      const int row_l = mt * 16 + r, key = r & 7;
      const uint4 p0 = *(const uint4*)&Apk[row_l][(((2*g)   ^ key) << 2)];
      const uint4 p1 = *(const uint4*)&Apk[row_l][(((2*g+1) ^ key) << 2)];
      const unsigned int pw[8] = {p0.x,p0.y,p0.z,p0.w,p1.x,p1.y,p1.z,p1.w};
      bf16x8 ah, al;
      #pragma unroll
      for (int e = 0; e < 8; ++e) { ah[e] = (short)(pw[e] >> 16); al[e] = (short)(pw[e] & 0xffffu); }
      #pragma unroll
      for (int ntl = 0; ntl < 5; ++ntl) {
        acc[mt][ntl] = __builtin_amdgcn_mfma_f32_16x16x32_bf16(ah, bh[ntl], acc[mt][ntl], 0,0,0);
        acc[mt][ntl] = __builtin_amdgcn_mfma_f32_16x16x32_bf16(al, bh[ntl], acc[mt][ntl], 0,0,0);
        acc[mt][ntl] = __builtin_amdgcn_mfma_f32_16x16x32_bf16(ah, bl[ntl], acc[mt][ntl], 0,0,0);
      }
    }
    __syncthreads();
  }
  #pragma unroll
  for (int mt = 0; mt < 4; ++mt)
    #pragma unroll
    for (int ntl = 0; ntl < 5; ++ntl) {
      const int cc = w * 80 + ntl * 16 + r;
      if (cc < 300) {
        uint4 pv;
        unsigned int* pp = (unsigned int*)&pv;
        #pragma unroll
        for (int q = 0; q < 4; ++q) {
          const float v = acc[mt][ntl][q];
          const unsigned short h = f2bf(v);
          pp[q] = ((unsigned int)h << 16) | f2bf(v - bf2f(h));
        }
        *(uint4*)&slab[(size_t)cc * 128 + row0 + mt * 16 + (g << 2)] = pv;
      }
    }
  #pragma unroll
  for (int mt = 0; mt < 4; ++mt) {
    #pragma unroll
    for (int q = 0; q < 4; ++q) {
      float sv = 0.f, dv = 0.f;
      #pragma unroll
      for (int ntl = 0; ntl < 5; ++ntl) {
        const int cc = w * 80 + ntl * 16 + r;
        const float a = acc[mt][ntl][q];
        sv += a * aosl[cc]; dv += a * aodl[cc];
      }
      #pragma unroll
      for (int s = 1; s <= 8; s <<= 1) { sv += __shfl_xor(sv, s); dv += __shfl_xor(dv, s); }
      if (r == 0) {
        const int row_l = mt * 16 + g * 4 + q;
        sred[w][row_l] = sv; dred[w][row_l] = dv;
      }
    }
  }
  __syncthreads();
  if (t < 64) {
    s2g[(size_t)b * 128 + row0 + t] = sred[0][t] + sred[1][t] + sred[2][t] + sred[3][t];
    d2g[(size_t)b * 128 + row0 + t] = dred[0][t] + dred[1][t] + dred[2][t] + dred[3][t];
  }
}

// =============== att2 + elu + log_softmax(features) + mean (rank-1) ===============
__global__ __launch_bounds__(256) void k_att2(
    const unsigned int* __restrict__ buf1, const u64* __restrict__ mg,
    const float* __restrict__ s2g, const float* __restrict__ d2g,
    float* __restrict__ gat)
{
  __shared__ unsigned short Th[16][64][8], Tl[16][64][8];
  __shared__ float sarr[128], darr[128];
  __shared__ u64 mAr[128], mBr[128];
  __shared__ float colsum[304];
  __shared__ float srow[16];
  const int t = threadIdx.x, lane = t & 63, w = t >> 6, r = lane & 15, g = lane >> 4;
  const int b = blockIdx.x;
  const unsigned int* slab = buf1 + (size_t)b * 61440;

  if (t < 128) {
    sarr[t] = s2g[(size_t)b * 128 + t];
    darr[t] = d2g[(size_t)b * 128 + t];
    mAr[t] = mg[((size_t)b * 128 + t) * 2];
    mBr[t] = mg[((size_t)b * 128 + t) * 2 + 1];
  }
  for (int c = t; c < 304; c += 256) colsum[c] = 0.f;
  __syncthreads();
  bf16x8 pah[2][4], pal[2][4];
  float inv2[2];
  #pragma unroll
  for (int mt = 0; mt < 2; ++mt) {
    const int i = w * 32 + mt * 16 + r;
    inv2[mt] = make_att_frags(sarr[i], mAr[i], mBr[i], darr, g, pah[mt], pal[mt]);
  }
  float scq[2][4];
  #pragma unroll
  for (int mt = 0; mt < 2; ++mt)
    #pragma unroll
    for (int q = 0; q < 4; ++q) scq[mt][q] = __shfl(inv2[mt], g * 4 + q);

  float m8[2][4], l8[2][4];
  #pragma unroll
  for (int mt = 0; mt < 2; ++mt)
    #pragma unroll
    for (int q = 0; q < 4; ++q) { m8[mt][q] = -3e38f; l8[mt][q] = 0.f; }

  for (int ch = 0; ch < 5; ++ch) {
    #pragma unroll
    for (int ii = 0; ii < 4; ++ii) {
      const int idx = t + ii * 256;
      const int c = idx & 63, jg = idx >> 6;
      const int gc = ch * 64 + c;
      uint4 p0 = {0,0,0,0}, p1 = {0,0,0,0};
      if (gc < 300) {
        const uint4* src = (const uint4*)&slab[(size_t)gc * 128 + jg * 8];
        p0 = src[0]; p1 = src[1];
      }
      const unsigned int pw[8] = {p0.x,p0.y,p0.z,p0.w,p1.x,p1.y,p1.z,p1.w};
      u16x8 hv, lv;
      #pragma unroll
      for (int e = 0; e < 8; ++e) { hv[e] = (unsigned short)(pw[e] >> 16); lv[e] = (unsigned short)(pw[e] & 0xffffu); }
      const int tile = ((c >> 4) << 2) | (jg >> 2);
      const int li = ((jg & 3) << 4) | (c & 15);
      *(u16x8*)&Th[tile][li][0] = hv;
      *(u16x8*)&Tl[tile][li][0] = lv;
    }
    __syncthreads();
    f32x4 pacc[2][4];
    #pragma unroll
    for (int mt = 0; mt < 2; ++mt)
      #pragma unroll
      for (int nt = 0; nt < 4; ++nt) pacc[mt][nt] = (f32x4){0.f,0.f,0.f,0.f};
    #pragma unroll
    for (int kt = 0; kt < 4; ++kt)
      #pragma unroll
      for (int nt = 0; nt < 4; ++nt) {
        const bf16x8 bh = *(const bf16x8*)&Th[(nt << 2) | kt][lane][0];
        const bf16x8 bl = *(const bf16x8*)&Tl[(nt << 2) | kt][lane][0];
        #pragma unroll
        for (int mt = 0; mt < 2; ++mt) {
          pacc[mt][nt] = __builtin_amdgcn_mfma_f32_16x16x32_bf16(pah[mt][kt], bh, pacc[mt][nt], 0,0,0);
          pacc[mt][nt] = __builtin_amdgcn_mfma_f32_16x16x32_bf16(pal[mt][kt], bh, pacc[mt][nt], 0,0,0);
          pacc[mt][nt] = __builtin_amdgcn_mfma_f32_16x16x32_bf16(pah[mt][kt], bl, pacc[mt][nt], 0,0,0);
        }
      }
    float csA[4] = {0,0,0,0};
    #pragma unroll
    for (int mt = 0; mt < 2; ++mt) {
      float vq[4][4];
      #pragma unroll
      for (int nt = 0; nt < 4; ++nt) {
        const int cc = ch * 64 + nt * 16 + r;
        const bool cv = cc < 300;
        #pragma unroll
        for (int q = 0; q < 4; ++q) {
          float v = pacc[mt][nt][q] * scq[mt][q];
          v = v > 0.f ? v : __expf(v) - 1.f;
          vq[nt][q] = cv ? v : -3e38f;
          csA[nt] += cv ? v : 0.f;
        }
      }
      #pragma unroll
      for (int q = 0; q < 4; ++q) {
        float mx = fmaxf(fmaxf(vq[0][q], vq[1][q]), fmaxf(vq[2][q], vq[3][q]));
        mx = fmaxf(mx, __shfl_xor(mx, 1));
        mx = fmaxf(mx, __shfl_xor(mx, 2));
        mx = fmaxf(mx, __shfl_xor(mx, 4));
        mx = fmaxf(mx, __shfl_xor(mx, 8));
        const float nm = fmaxf(m8[mt][q], mx);
        float ps = __expf(vq[0][q]-nm) + __expf(vq[1][q]-nm) + __expf(vq[2][q]-nm) + __expf(vq[3][q]-nm);
        ps += __shfl_xor(ps, 1); ps += __shfl_xor(ps, 2);
        ps += __shfl_xor(ps, 4); ps += __shfl_xor(ps, 8);
        l8[mt][q] = l8[mt][q] * __expf(m8[mt][q] - nm) + ps;
        m8[mt][q] = nm;
      }
    }
    #pragma unroll
    for (int nt = 0; nt < 4; ++nt) {
      float cs = csA[nt];
      cs += __shfl_xor(cs, 16); cs += __shfl_xor(cs, 32);
      const int cc = ch * 64 + nt * 16 + r;
      if (g == 0 && cc < 300) atomicAdd(&colsum[cc], cs);
    }
    __syncthreads();
  }
  if (r == 0) {
    float sp = 0.f;
    #pragma unroll
    for (int mt = 0; mt < 2; ++mt)
      #pragma unroll
      for (int q = 0; q < 4; ++q) sp += m8[mt][q] + __logf(l8[mt][q]);
    srow[w * 4 + g] = sp;
  }
  __syncthreads();
  float S = 0.f;
  #pragma unroll
  for (int k = 0; k < 16; ++k) S += srow[k];
  for (int c = t; c < 300; c += 256)
    gat[(size_t)b * 300 + c] = (colsum[c] - S) * (1.f / 128.f);
}

// =============== split-K GEMM: P[sk][M][N] = A_chunk @ B_chunk (64x64 tile) ===============
__global__ __launch_bounds__(256) void k_gemm_sk(
    const float* __restrict__ A, const float* __restrict__ B,
    float* __restrict__ P, int M, int K, int N, int kpt)
{
  __shared__ unsigned short Ah[64][40], Al[64][40], Bh[64][40], Bl[64][40];
  const int t = threadIdx.x, lane = t & 63, w = t >> 6, r = lane & 15, g = lane >> 4;
  const int row0 = blockIdx.x * 64, col0 = blockIdx.y * 64;
  const int sk = blockIdx.z;
  const int k0 = sk * kpt * 32;
  const int kend = min(K, k0 + kpt * 32);

  f32x4 acc[4];
  #pragma unroll
  for (int nt = 0; nt < 4; ++nt) acc[nt] = (f32x4){0.f,0.f,0.f,0.f};

  for (int kt = k0; kt < kend; kt += 32) {
    #pragma unroll
    for (int ii = 0; ii < 2; ++ii) {
      const int idx = t + ii * 256, ar = idx >> 3, aq = (idx & 7) * 4, gk = kt + aq;
      const float* ap = &A[(size_t)(row0 + ar) * K + gk];
      float v0 = gk     < kend ? ap[0] : 0.f;
      float v1 = gk + 1 < kend ? ap[1] : 0.f;
      float v2 = gk + 2 < kend ? ap[2] : 0.f;
      float v3 = gk + 3 < kend ? ap[3] : 0.f;
      unsigned short h0=f2bf(v0),h1=f2bf(v1),h2=f2bf(v2),h3=f2bf(v3);
      *(unsigned int*)&Ah[ar][aq]   = h0 | ((unsigned int)h1 << 16);
      *(unsigned int*)&Ah[ar][aq+2] = h2 | ((unsigned int)h3 << 16);
      unsigned short l0=f2bf(v0-bf2f(h0)),l1=f2bf(v1-bf2f(h1)),l2=f2bf(v2-bf2f(h2)),l3=f2bf(v3-bf2f(h3));
      *(unsigned int*)&Al[ar][aq]   = l0 | ((unsigned int)l1 << 16);
      *(unsigned int*)&Al[ar][aq+2] = l2 | ((unsigned int)l3 << 16);
    }
    #pragma unroll
    for (int ii = 0; ii < 4; ++ii) {
      const int idx = t + ii * 256, n = idx & 63, kk = (idx >> 6) * 2;
      const int gn = col0 + n;
      float v0 = (gn < N && kt + kk     < kend) ? B[(size_t)(kt + kk) * N + gn] : 0.f;
      float v1 = (gn < N && kt + kk + 1 < kend) ? B[(size_t)(kt + kk + 1) * N + gn] : 0.f;
      unsigned short h0 = f2bf(v0), h1 = f2bf(v1);
      *(unsigned int*)&Bh[n][kk] = h0 | ((unsigned int)h1 << 16);
      unsigned short l0 = f2bf(v0 - bf2f(h0)), l1 = f2bf(v1 - bf2f(h1));
      *(unsigned int*)&Bl[n][kk] = l0 | ((unsigned int)l1 << 16);
    }
    __syncthreads();
    const bf16x8 ah  = *(const bf16x8*)&Ah[w * 16 + r][g * 8];
    const bf16x8 al2 = *(const bf16x8*)&Al[w * 16 + r][g * 8];
    #pragma unroll
    for (int nt = 0; nt < 4; ++nt) {
      const bf16x8 bh = *(const bf16x8*)&Bh[nt * 16 + r][g * 8];
      const bf16x8 bl = *(const bf16x8*)&Bl[nt * 16 + r][g * 8];
      acc[nt] = __builtin_amdgcn_mfma_f32_16x16x32_bf16(ah,  bh, acc[nt], 0,0,0);
      acc[nt] = __builtin_amdgcn_mfma_f32_16x16x32_bf16(al2, bh, acc[nt], 0,0,0);
      acc[nt] = __builtin_amdgcn_mfma_f32_16x16x32_bf16(ah,  bl, acc[nt], 0,0,0);
    }
    __syncthreads();
  }
  float* Pout = P + (size_t)sk * M * N;
  #pragma unroll
  for (int nt = 0; nt < 4; ++nt) {
    const int cc = col0 + nt * 16 + r;
    if (cc < N) {
      #pragma unroll
      for (int q = 0; q < 4; ++q)
        Pout[(size_t)(row0 + w * 16 + g * 4 + q) * N + cc] = acc[nt][q];
    }
  }
}

// =============== split-K GEMM with FUSED reduce-A: A = act(Σ_s P[s] + bias) ===============
// Logical A[M][K]: k < NA from (PA,nskA,biasA,actA); k >= NA from (PB,nskB,biasB,actB).
// Sum order identical to k_reduce (bias first, sk ascending) -> bit-identical.
__global__ __launch_bounds__(256) void k_gemm_skr(
    const float* __restrict__ PA, int nskA, const float* __restrict__ biasA, int actA, int NA,
    const float* __restrict__ PB, int nskB, const float* __restrict__ biasB, int actB,
    const float* __restrict__ B, float* __restrict__ P, int M, int K, int N, int kpt)
{
  __shared__ unsigned short Ah[64][40], Al[64][40], Bh[64][40], Bl[64][40];
  const int t = threadIdx.x, lane = t & 63, w = t >> 6, r = lane & 15, g = lane >> 4;
  const int row0 = blockIdx.x * 64, col0 = blockIdx.y * 64;
  const int sk = blockIdx.z;
  const int k0 = sk * kpt * 32;
  const int kend = min(K, k0 + kpt * 32);
  const int NB = K - NA;

  f32x4 acc[4];
  #pragma unroll
  for (int nt = 0; nt < 4; ++nt) acc[nt] = (f32x4){0.f,0.f,0.f,0.f};

  for (int kt = k0; kt < kend; kt += 32) {
    #pragma unroll
    for (int ii = 0; ii < 2; ++ii) {
      const int idx = t + ii * 256, ar = idx >> 3, aq = (idx & 7) * 4, gk = kt + aq;
      const int row = row0 + ar;
      float v[4];
      #pragma unroll
      for (int e = 0; e < 4; ++e) {
        const int k = gk + e;
        float s = 0.f;
        if (k < kend) {
          if (k < NA) {
            s = biasA[k];
            for (int s2 = 0; s2 < nskA; ++s2)
              s += PA[(size_t)s2 * M * NA + (size_t)row * NA + k];
            if (actA) s = fmaxf(s, 0.f);
          } else {
            const int k2 = k - NA;
            s = biasB[k2];
            for (int s2 = 0; s2 < nskB; ++s2)
              s += PB[(size_t)s2 * M * NB + (size_t)row * NB + k2];
            if (actB) s = fmaxf(s, 0.f);
          }
        }
        v[e] = s;
      }
      unsigned short h0=f2bf(v[0]),h1=f2bf(v[1]),h2=f2bf(v[2]),h3=f2bf(v[3]);
      *(unsigned int*)&Ah[ar][aq]   = h0 | ((unsigned int)h1 << 16);
      *(unsigned int*)&Ah[ar][aq+2] = h2 | ((unsigned int)h3 << 16);
      unsigned short l0=f2bf(v[0]-bf2f(h0)),l1=f2bf(v[1]-bf2f(h1)),l2=f2bf(v[2]-bf2f(h2)),l3=f2bf(v[3]-bf2f(h3));
      *(unsigned int*)&Al[ar][aq]   = l0 | ((unsigned int)l1 << 16);
      *(unsigned int*)&Al[ar][aq+2] = l2 | ((unsigned int)l3 << 16);
    }
    #pragma unroll
    for (int ii = 0; ii < 4; ++ii) {
      const int idx = t + ii * 256, n = idx & 63, kk = (idx >> 6) * 2;
      const int gn = col0 + n;
      float v0 = (gn < N && kt + kk     < kend) ? B[(size_t)(kt + kk) * N + gn] : 0.f;
      float v1 = (gn < N && kt + kk + 1 < kend) ? B[(size_t)(kt + kk + 1) * N + gn] : 0.f;
      unsigned short h0 = f2bf(v0), h1 = f2bf(v1);
      *(unsigned int*)&Bh[n][kk] = h0 | ((unsigned int)h1 << 16);
      unsigned short l0 = f2bf(v0 - bf2f(h0)), l1 = f2bf(v1 - bf2f(h1));
      *(unsigned int*)&Bl[n][kk] = l0 | ((unsigned int)l1 << 16);
    }
    __syncthreads();
    const bf16x8 ah  = *(const bf16x8*)&Ah[w * 16 + r][g * 8];
    const bf16x8 al2 = *(const bf16x8*)&Al[w * 16 + r][g * 8];
    #pragma unroll
    for (int nt = 0; nt < 4; ++nt) {
      const bf16x8 bh = *(const bf16x8*)&Bh[nt * 16 + r][g * 8];
      const bf16x8 bl = *(const bf16x8*)&Bl[nt * 16 + r][g * 8];
      acc[nt] = __builtin_amdgcn_mfma_f32_16x16x32_bf16(ah,  bh, acc[nt], 0,0,0);
      acc[nt] = __builtin_amdgcn_mfma_f32_16x16x32_bf16(al2, bh, acc[nt], 0,0,0);
      acc[nt] = __builtin_amdgcn_mfma_f32_16x16x32_bf16(ah,  bl, acc[nt], 0,0,0);
    }
    __syncthreads();
  }
  float* Pout = P + (size_t)sk * M * N;
  #pragma unroll
  for (int nt = 0; nt < 4; ++nt) {
    const int cc = col0 + nt * 16 + r;
    if (cc < N) {
      #pragma unroll
      for (int q = 0; q < 4; ++q)
        Pout[(size_t)(row0 + w * 16 + g * 4 + q) * N + cc] = acc[nt][q];
    }
  }
}

// =============== final: reduce P4 + bias + relu + GEMV + sigmoid ===============
__global__ __launch_bounds__(512) void k_out(
    const float* __restrict__ P4, const float* __restrict__ f1b,
    const float* __restrict__ w2, const float* __restrict__ b2,
    float* __restrict__ out)
{
  const int t = threadIdx.x, lane = t & 63, w = t >> 6;
  const int b = blockIdx.x * 8 + w;
  float p = 0.f;
  for (int k = lane; k < 300; k += 64) {
    float s = f1b[k];
    #pragma unroll
    for (int s2 = 0; s2 < 4; ++s2)
      s += P4[(size_t)s2 * 512 * 300 + (size_t)b * 300 + k];
    s = fmaxf(s, 0.f);
    p += s * w2[k];
  }
  p = warp_sum(p);
  if (lane == 0) out[b] = 1.f / (1.f + __expf(-(p + b2[0])));
}

extern "C" void kernel_launch(void* const* d_in, const int* in_sizes, int n_in,
                              void* d_out, int out_size, void* d_ws, size_t ws_size,
                              hipStream_t stream)
{
  const float* x    = (const float*)d_in[0];
  const int*   adj  = (const int*)d_in[1];
  const float* fp   = (const float*)d_in[2];
  const float* Whw  = (const float*)d_in[3];
  const float* asrc = (const float*)d_in[4];
  const float* adst = (const float*)d_in[5];
  const float* Wout = (const float*)d_in[6];
  const float* aos  = (const float*)d_in[7];
  const float* aod  = (const float*)d_in[8];
  const float* fc1w = (const float*)d_in[9];
  const float* fc1b = (const float*)d_in[10];
  const float* fc2w = (const float*)d_in[11];
  const float* fc2b = (const float*)d_in[12];
  const float* fcgw = (const float*)d_in[13];
  const float* fcgb = (const float*)d_in[14];
  const float* fcfw = (const float*)d_in[15];
  const float* fcfb = (const float*)d_in[16];
  const float* f1w  = (const float*)d_in[17];
  const float* f1b  = (const float*)d_in[18];
  const float* f2w  = (const float*)d_in[19];
  const float* f2b  = (const float*)d_in[20];
  float* out = (float*)d_out;

  char* wsb = (char*)d_ws;
  unsigned int* buf1 = (unsigned int*)wsb;
  float* s1g = (float*)(wsb + 125829120);
  float* d1g = (float*)(wsb + 127926272);
  float* s2g = (float*)(wsb + 130023424);
  float* d2g = (float*)(wsb + 130285568);
  u64*   mgb = (u64*)  (wsb + 130547712);
  float* gatp = (float*)(wsb + 131596288);
  float* P0 = (float*)(wsb + 135716864);
  float* P1 = (float*)(wsb + 142008320);
  float* P2 = (float*)(wsb + 144465920);
  float* P3 = (float*)(wsb + 145694720);
  float* P4 = (float*)(wsb + 146923520);
  unsigned short* Bf1H = (unsigned short*)(wsb + 149381120);
  unsigned short* Bf1L = (unsigned short*)(wsb + 149544960);
  unsigned short* Bf2H = (unsigned short*)(wsb + 149708800);
  unsigned short* Bf2L = (unsigned short*)(wsb + 150016000);

  k_prep1<<<dim3(5, 32), 64, 0, stream>>>(Whw, Bf1H, Bf1L);
  k_prep2<<<dim3(15, 20), 64, 0, stream>>>(Wout, Bf2H, Bf2L);
  k_mask <<<512, 256, 0, stream>>>(adj, mgb);
  // --- GAT chain (unchanged from 359 µs baseline) ---
  k_gemm1<<<2048, 512, 0, stream>>>(x, Bf1H, Bf1L, asrc, adst, buf1, s1g, d1g);
  k_att1 <<<4096, 256, 0, stream>>>(buf1, mgb, s1g, d1g);
  k_gemm2<<<1024, 256, 0, stream>>>(buf1, Bf2H, Bf2L, aos, aod, s2g, d2g);
  k_att2 <<<512, 256, 0, stream>>>(buf1, mgb, s2g, d2g, gatp);
  // --- head chain: split-K GEMMs with fused reductions (6 k_reduce launches removed) ---
  // fc1: P0 = fp @ fc1w
  k_gemm_sk<<<dim3(8,8,6), 256, 0, stream>>>(fp, fc1w, P0, 512, 1489, 512, 8);
  // fc2: P1 = relu(reduce(P0)+fc1b) @ fc2w
  k_gemm_skr<<<dim3(8,5,4), 256, 0, stream>>>(P0, 6, fc1b, 1, 512,
                                              nullptr, 0, nullptr, 0,
                                              fc2w, P1, 512, 512, 300, 4);
  // fcg: P2 = gatp @ fcgw
  k_gemm_sk<<<dim3(8,5,2), 256, 0, stream>>>(gatp, fcgw, P2, 512, 300, 300, 5);
  // fcf: P3 = (reduce(P1)+fc2b) @ fcfw
  k_gemm_skr<<<dim3(8,5,2), 256, 0, stream>>>(P1, 4, fc2b, 0, 300,
                                              nullptr, 0, nullptr, 0,
                                              fcfw, P3, 512, 300, 300, 5);
  // ffn1: P4 = [relu(reduce(P2)+fcgb) | relu(reduce(P3)+fcfb)] @ f1w
  k_gemm_skr<<<dim3(8,5,4), 256, 0, stream>>>(P2, 2, fcgb, 1, 300,
                                              P3, 2, fcfb, 1,
                                              f1w, P4, 512, 600, 300, 5);
  // out: sigmoid(relu(reduce(P4)+f1b) . w2 + b2)
  k_out<<<64, 512, 0, stream>>>(P4, f1b, f2w, f2b, out);
}

// Round 17
// 341.232 us; speedup vs baseline: 1.1816x; 1.1816x over previous
//
#include <hip/hip_runtime.h>
#include <hip/hip_bf16.h>
#include <math.h>
#include <stdint.h>

#define LRA 0.2f

typedef __attribute__((ext_vector_type(8))) short bf16x8;
typedef __attribute__((ext_vector_type(8))) unsigned short u16x8;
typedef __attribute__((ext_vector_type(4))) float f32x4;
typedef unsigned long long u64;

__device__ __forceinline__ unsigned short f2bf(float v) {
  union { __hip_bfloat16 b; unsigned short u; } c;
  c.b = __float2bfloat16(v);
  return c.u;
}
__device__ __forceinline__ float bf2f(unsigned short h) {
  union { float f; unsigned int u; } a; a.u = ((unsigned int)h) << 16;
  return a.f;
}
__device__ __forceinline__ float warp_sum(float v){
  #pragma unroll
  for (int s = 32; s; s >>= 1) v += __shfl_xor(v, s);
  return v;
}

// =============== adjacency -> bitmasks (once) ===============
__global__ __launch_bounds__(256) void k_mask(const int* __restrict__ adj, u64* __restrict__ mg){
  const int t = threadIdx.x, lane = t & 63, w = t >> 6, b = blockIdx.x;
  const int* adjb = adj + (size_t)b * 128 * 128;
  for (int i = w * 32; i < w * 32 + 32; ++i) {
    u64 b0 = __ballot(adjb[i * 128 + lane] > 0);
    u64 b1 = __ballot(adjb[i * 128 + 64 + lane] > 0);
    if (lane == 0) { mg[((size_t)b * 128 + i) * 2] = b0; mg[((size_t)b * 128 + i) * 2 + 1] = b1; }
  }
}

// =============== prep: W_heads -> fragment-layout hi/lo ===============
__global__ __launch_bounds__(64) void k_prep1(
    const float* __restrict__ Whw, unsigned short* __restrict__ BH, unsigned short* __restrict__ BL)
{
  const int kt = blockIdx.x, nt = blockIdx.y, l = threadIdx.x;
  const int n = nt * 16 + (l & 15), k0 = kt * 32 + (l >> 4) * 8;
  const int hd = n / 60, j = n - hd * 60;
  uint4 hv, lv;
  unsigned int* hp = (unsigned int*)&hv;
  unsigned int* lp = (unsigned int*)&lv;
  #pragma unroll
  for (int p = 0; p < 4; ++p) {
    unsigned short hh[2], ll[2];
    #pragma unroll
    for (int e = 0; e < 2; ++e) {
      const int k = k0 + p * 2 + e;
      const float v = (n < 480 && k < 133) ? Whw[((size_t)hd * 133 + k) * 60 + j] : 0.f;
      const unsigned short h = f2bf(v);
      hh[e] = h; ll[e] = f2bf(v - bf2f(h));
    }
    hp[p] = hh[0] | ((unsigned int)hh[1] << 16);
    lp[p] = ll[0] | ((unsigned int)ll[1] << 16);
  }
  const size_t off = (((size_t)(kt * 32 + nt)) * 64 + l) * 8;
  *(uint4*)&BH[off] = hv;
  *(uint4*)&BL[off] = lv;
}

// =============== prep: Wout -> fragment-layout hi/lo ===============
__global__ __launch_bounds__(64) void k_prep2(
    const float* __restrict__ W, unsigned short* __restrict__ BH, unsigned short* __restrict__ BL)
{
  const int kt = blockIdx.x, nt = blockIdx.y, l = threadIdx.x;
  const int n = nt * 16 + (l & 15), k0 = kt * 32 + (l >> 4) * 8;
  uint4 hv, lv;
  unsigned int* hp = (unsigned int*)&hv;
  unsigned int* lp = (unsigned int*)&lv;
  #pragma unroll
  for (int p = 0; p < 4; ++p) {
    unsigned short hh[2], ll[2];
    #pragma unroll
    for (int e = 0; e < 2; ++e) {
      const int k = k0 + p * 2 + e;
      const float v = (n < 300 && k < 480) ? W[(size_t)k * 300 + n] : 0.f;
      const unsigned short h = f2bf(v);
      hh[e] = h; ll[e] = f2bf(v - bf2f(h));
    }
    hp[p] = hh[0] | ((unsigned int)hh[1] << 16);
    lp[p] = ll[0] | ((unsigned int)ll[1] << 16);
  }
  const size_t off = (((size_t)(kt * 20 + nt)) * 64 + l) * 8;
  *(uint4*)&BH[off] = hv;
  *(uint4*)&BL[off] = lv;
}

// =============== GEMM1: Wh = x @ Bcat; 4 row-parts per batch ===============
__global__ __launch_bounds__(512) void k_gemm1(
    const float* __restrict__ x,
    const unsigned short* __restrict__ BH, const unsigned short* __restrict__ BL,
    const float* __restrict__ asrc, const float* __restrict__ adst,
    unsigned int* __restrict__ buf1, float* __restrict__ s1g, float* __restrict__ d1g)
{
  __shared__ unsigned int Apk[32][32];
  __shared__ float asl[512], adl[512];
  __shared__ float sp0[8][32], sp1[8][32], dp0[8][32], dp1[8][32];
  const int t = threadIdx.x, lane = t & 63, w = t >> 6, r = lane & 15, g = lane >> 4;
  const int b = blockIdx.x >> 2, p = blockIdx.x & 3;
  const int row0 = p * 32;
  const float* xb = x + (size_t)b * 128 * 133;
  unsigned int* slab = buf1 + (size_t)b * 61440;

  asl[t] = (t < 480) ? asrc[t] : 0.f;
  adl[t] = (t < 480) ? adst[t] : 0.f;

  f32x4 acc[2][4];
  #pragma unroll
  for (int mt = 0; mt < 2; ++mt)
    #pragma unroll
    for (int ntl = 0; ntl < 4; ++ntl) acc[mt][ntl] = (f32x4){0.f,0.f,0.f,0.f};

  for (int kt = 0; kt < 5; ++kt) {
    if (t < 256) {
      const int row_l = t >> 3, sl = t & 7;
      const int k0 = kt * 32 + sl * 4;
      uint4 pk;
      unsigned int* pp = (unsigned int*)&pk;
      #pragma unroll
      for (int e = 0; e < 4; ++e) {
        const int k = k0 + e;
        const float v = (k < 133) ? xb[(size_t)(row0 + row_l) * 133 + k] : 0.f;
        const unsigned short h = f2bf(v);
        pp[e] = ((unsigned int)h << 16) | f2bf(v - bf2f(h));
      }
      *(uint4*)&Apk[row_l][((sl ^ (row_l & 7)) << 2)] = pk;
    }
    bf16x8 bh[4], bl[4];
    #pragma unroll
    for (int ntl = 0; ntl < 4; ++ntl) {
      const int nt = w * 4 + ntl;
      const size_t off = (((size_t)(kt * 32 + nt)) * 64 + lane) * 8;
      bh[ntl] = *(const bf16x8*)&BH[off];
      bl[ntl] = *(const bf16x8*)&BL[off];
    }
    __syncthreads();
    #pragma unroll
    for (int mt = 0; mt < 2; ++mt) {
      const int row_l = mt * 16 + r, key = r & 7;
      const uint4 p0 = *(const uint4*)&Apk[row_l][(((2*g)   ^ key) << 2)];
      const uint4 p1 = *(const uint4*)&Apk[row_l][(((2*g+1) ^ key) << 2)];
      const unsigned int pw[8] = {p0.x,p0.y,p0.z,p0.w,p1.x,p1.y,p1.z,p1.w};
      bf16x8 ah, al;
      #pragma unroll
      for (int e = 0; e < 8; ++e) { ah[e] = (short)(pw[e] >> 16); al[e] = (short)(pw[e] & 0xffffu); }
      #pragma unroll
      for (int ntl = 0; ntl < 4; ++ntl) {
        acc[mt][ntl] = __builtin_amdgcn_mfma_f32_16x16x32_bf16(ah, bh[ntl], acc[mt][ntl], 0,0,0);
        acc[mt][ntl] = __builtin_amdgcn_mfma_f32_16x16x32_bf16(al, bh[ntl], acc[mt][ntl], 0,0,0);
        acc[mt][ntl] = __builtin_amdgcn_mfma_f32_16x16x32_bf16(ah, bl[ntl], acc[mt][ntl], 0,0,0);
      }
    }
    __syncthreads();
  }
  #pragma unroll
  for (int mt = 0; mt < 2; ++mt)
    #pragma unroll
    for (int ntl = 0; ntl < 4; ++ntl) {
      const int cc = (w * 4 + ntl) * 16 + r;
      if (cc < 480) {
        const int hd = cc / 60, cl = cc - hd * 60;
        uint4 pv;
        unsigned int* pp = (unsigned int*)&pv;
        #pragma unroll
        for (int q = 0; q < 4; ++q) {
          const float v = acc[mt][ntl][q];
          const unsigned short h = f2bf(v);
          pp[q] = ((unsigned int)h << 16) | f2bf(v - bf2f(h));
        }
        *(uint4*)&slab[(size_t)hd * 7680 + (size_t)cl * 128 + row0 + mt * 16 + (g << 2)] = pv;
      }
    }
  const int thr0 = 60 - 4 * w;
  #pragma unroll
  for (int mt = 0; mt < 2; ++mt) {
    #pragma unroll
    for (int q = 0; q < 4; ++q) {
      float s0 = 0.f, s1 = 0.f, d0 = 0.f, d1 = 0.f;
      #pragma unroll
      for (int ntl = 0; ntl < 4; ++ntl) {
        const int loc = ntl * 16 + r;
        const int cc = w * 64 + loc;
        const float a = acc[mt][ntl][q];
        const float as = asl[cc], ad = adl[cc];
        if (loc < thr0) { s0 += a * as; d0 += a * ad; }
        else            { s1 += a * as; d1 += a * ad; }
      }
      #pragma unroll
      for (int s = 1; s <= 8; s <<= 1) {
        s0 += __shfl_xor(s0, s); s1 += __shfl_xor(s1, s);
        d0 += __shfl_xor(d0, s); d1 += __shfl_xor(d1, s);
      }
      if (r == 0) {
        const int row_l = mt * 16 + g * 4 + q;
        sp0[w][row_l] = s0; sp1[w][row_l] = s1;
        dp0[w][row_l] = d0; dp1[w][row_l] = d1;
      }
    }
  }
  __syncthreads();
  if (t < 256) {
    const int hd = t >> 5, row_l = t & 31;
    s1g[((size_t)b * 8 + hd) * 128 + row0 + row_l] = sp0[hd][row_l] + (hd > 0 ? sp1[hd-1][row_l] : 0.f);
    d1g[((size_t)b * 8 + hd) * 128 + row0 + row_l] = dp0[hd][row_l] + (hd > 0 ? dp1[hd-1][row_l] : 0.f);
  }
}

// ===== merged attention-fragment generator (shared by att1/att2) =====
__device__ __forceinline__ float make_att_frags(
    const float si, const u64 ma, const u64 mb2, const float* darr,
    const int g, bf16x8* pah, bf16x8* pal)
{
  const unsigned int mby[4] = {
    (unsigned int)(ma  >> (g * 8)) & 0xffu,
    (unsigned int)(ma  >> (32 + g * 8)) & 0xffu,
    (unsigned int)(mb2 >> (g * 8)) & 0xffu,
    (unsigned int)(mb2 >> (32 + g * 8)) & 0xffu };
  float ev[4][8];
  float mx = -3e38f;
  #pragma unroll
  for (int kt = 0; kt < 4; ++kt)
    #pragma unroll
    for (int e = 0; e < 8; ++e) {
      const int j = ((kt & 1) * 32) + ((kt >> 1) * 64) + g * 8 + e;
      float v = si + darr[j];
      v = fmaxf(v, LRA * v);
      const float vv = (mby[((kt & 1) << 1) | (kt >> 1)] & (1u << e)) ? v : -3e38f;
      ev[kt][e] = vv;
      mx = fmaxf(mx, vv);
    }
  mx = fmaxf(mx, __shfl_xor(mx, 16));
  mx = fmaxf(mx, __shfl_xor(mx, 32));
  float sum = 0.f;
  #pragma unroll
  for (int kt = 0; kt < 4; ++kt)
    #pragma unroll
    for (int e = 0; e < 8; ++e) {
      const float p = (ev[kt][e] > -1e37f) ? __expf(ev[kt][e] - mx) : 0.f;
      ev[kt][e] = p;
      sum += p;
    }
  sum += __shfl_xor(sum, 16);
  sum += __shfl_xor(sum, 32);
  #pragma unroll
  for (int kt = 0; kt < 4; ++kt) {
    const int ks = ((kt & 1) << 1) | (kt >> 1);
    union { unsigned int u[4]; bf16x8 v; } hw, lw;
    #pragma unroll
    for (int p2 = 0; p2 < 4; ++p2) {
      const float p0 = ev[ks][2 * p2], p1 = ev[ks][2 * p2 + 1];
      const unsigned short h0 = f2bf(p0), h1 = f2bf(p1);
      hw.u[p2] = h0 | ((unsigned int)h1 << 16);
      lw.u[p2] = f2bf(p0 - bf2f(h0)) | ((unsigned int)f2bf(p1 - bf2f(h1)) << 16);
    }
    pah[kt] = hw.v;
    pal[kt] = lw.v;
  }
  return 1.f / sum;
}

// =============== att1: per (b,head); h = elu(att@Wh) in-place ===============
__global__ __launch_bounds__(256) void k_att1(
    unsigned int* __restrict__ buf1, const u64* __restrict__ mg,
    const float* __restrict__ s1g, const float* __restrict__ d1g)
{
  __shared__ unsigned short Th[16][64][8], Tl[16][64][8];
  __shared__ float sarr[128], darr[128];
  __shared__ u64 mAr[128], mBr[128];
  const int t = threadIdx.x, lane = t & 63, w = t >> 6, r = lane & 15, g = lane >> 4;
  const int bid = blockIdx.x;
  const int lb = ((bid & 7) << 9) | (bid >> 3);
  const int b = lb >> 3, hd = lb & 7;
  const size_t sl = (size_t)b * 8 + hd;
  unsigned int* slab = buf1 + sl * 7680;

  if (t < 128) {
    sarr[t] = s1g[sl * 128 + t];
    darr[t] = d1g[sl * 128 + t];
    mAr[t] = mg[((size_t)b * 128 + t) * 2];
    mBr[t] = mg[((size_t)b * 128 + t) * 2 + 1];
  }
  #pragma unroll
  for (int ii = 0; ii < 4; ++ii) {
    const int idx = t + ii * 256;
    const int c = idx & 63, jg = idx >> 6;
    uint4 p0 = {0,0,0,0}, p1 = {0,0,0,0};
    if (c < 60) {
      const uint4* src = (const uint4*)&slab[(size_t)c * 128 + jg * 8];
      p0 = src[0]; p1 = src[1];
    }
    const unsigned int pw[8] = {p0.x,p0.y,p0.z,p0.w,p1.x,p1.y,p1.z,p1.w};
    u16x8 hv, lv;
    #pragma unroll
    for (int e = 0; e < 8; ++e) { hv[e] = (unsigned short)(pw[e] >> 16); lv[e] = (unsigned short)(pw[e] & 0xffffu); }
    const int tile = ((c >> 4) << 2) | (jg >> 2);
    const int li = ((jg & 3) << 4) | (c & 15);
    *(u16x8*)&Th[tile][li][0] = hv;
    *(u16x8*)&Tl[tile][li][0] = lv;
  }
  __syncthreads();
  bf16x8 pah[2][4], pal[2][4];
  float inv2[2];
  #pragma unroll
  for (int mt = 0; mt < 2; ++mt) {
    const int i = w * 32 + mt * 16 + r;
    inv2[mt] = make_att_frags(sarr[i], mAr[i], mBr[i], darr, g, pah[mt], pal[mt]);
  }
  f32x4 acc[2][4];
  #pragma unroll
  for (int mt = 0; mt < 2; ++mt)
    #pragma unroll
    for (int nt = 0; nt < 4; ++nt) acc[mt][nt] = (f32x4){0.f,0.f,0.f,0.f};
  #pragma unroll
  for (int kt = 0; kt < 4; ++kt)
    #pragma unroll
    for (int nt = 0; nt < 4; ++nt) {
      const bf16x8 bh = *(const bf16x8*)&Th[(nt << 2) | kt][lane][0];
      const bf16x8 bl = *(const bf16x8*)&Tl[(nt << 2) | kt][lane][0];
      #pragma unroll
      for (int mt = 0; mt < 2; ++mt) {
        acc[mt][nt] = __builtin_amdgcn_mfma_f32_16x16x32_bf16(pah[mt][kt], bh, acc[mt][nt], 0,0,0);
        acc[mt][nt] = __builtin_amdgcn_mfma_f32_16x16x32_bf16(pal[mt][kt], bh, acc[mt][nt], 0,0,0);
        acc[mt][nt] = __builtin_amdgcn_mfma_f32_16x16x32_bf16(pah[mt][kt], bl, acc[mt][nt], 0,0,0);
      }
    }
  #pragma unroll
  for (int mt = 0; mt < 2; ++mt) {
    float sc[4];
    #pragma unroll
    for (int q = 0; q < 4; ++q) sc[q] = __shfl(inv2[mt], g * 4 + q);
    #pragma unroll
    for (int nt = 0; nt < 4; ++nt) {
      const int cc = nt * 16 + r;
      if (cc < 60) {
        #pragma unroll
        for (int q = 0; q < 4; ++q) {
          const int row = w * 32 + mt * 16 + g * 4 + q;
          float v = acc[mt][nt][q] * sc[q];
          v = v > 0.f ? v : __expf(v) - 1.f;
          const unsigned short h = f2bf(v), l = f2bf(v - bf2f(h));
          slab[(size_t)row * 60 + cc] = ((unsigned int)h << 16) | l;
        }
      }
    }
  }
}

// =============== GEMM2: Wo = h @ W_out; 2 row-parts (64 rows) per batch ===============
__global__ __launch_bounds__(256, 3) void k_gemm2(
    unsigned int* __restrict__ buf1,
    const unsigned short* __restrict__ BH, const unsigned short* __restrict__ BL,
    const float* __restrict__ aos, const float* __restrict__ aod,
    float* __restrict__ s2g, float* __restrict__ d2g)
{
  __shared__ unsigned int Apk[64][32];
  __shared__ float aosl[320], aodl[320];
  __shared__ float sred[4][64], dred[4][64];
  const int t = threadIdx.x, lane = t & 63, w = t >> 6, r = lane & 15, g = lane >> 4;
  const int b = blockIdx.x >> 1, p = blockIdx.x & 1;
  const int row0 = p * 64;
  unsigned int* slab = buf1 + (size_t)b * 61440;
  if (t < 320) { aosl[t] = t < 300 ? aos[t] : 0.f; aodl[t] = t < 300 ? aod[t] : 0.f; }

  f32x4 acc[4][5];
  #pragma unroll
  for (int mt = 0; mt < 4; ++mt)
    #pragma unroll
    for (int ntl = 0; ntl < 5; ++ntl) acc[mt][ntl] = (f32x4){0.f,0.f,0.f,0.f};

  for (int kt = 0; kt < 15; ++kt) {
    #pragma unroll
    for (int i = 0; i < 2; ++i) {
      const int idx = t + i * 256, row_l = idx >> 3, sl = idx & 7;
      const int k0 = kt * 32 + sl * 4;
      const int hd = k0 / 60, c = k0 - hd * 60;
      const uint4 v = *(const uint4*)&slab[(size_t)hd * 7680 + (size_t)(row0 + row_l) * 60 + c];
      *(uint4*)&Apk[row_l][((sl ^ (row_l & 7)) << 2)] = v;
    }
    bf16x8 bh[5], bl[5];
    #pragma unroll
    for (int ntl = 0; ntl < 5; ++ntl) {
      const int nt = w * 5 + ntl;
      const size_t off = (((size_t)(kt * 20 + nt)) * 64 + lane) * 8;
      bh[ntl] = *(const bf16x8*)&BH[off];
      bl[ntl] = *(const bf16x8*)&BL[off];
    }
    __syncthreads();
    #pragma unroll
    for (int mt = 0; mt < 4; ++mt) {
      const int row_l = mt * 16 + r, key = r & 7;
      const uint4 p0 = *(const uint4*)&Apk[row_l][(((2*g)   ^ key) << 2)];
      const uint4 p1 = *(const uint4*)&Apk[row_l][(((2*g+1) ^ key) << 2)];
      const unsigned int pw[8] = {p0.x,p0.y,p0.z,p0.w,p1.x,p1.y,p1.z,p1.w};
      bf16x8 ah, al;
      #pragma unroll
      for (int e = 0; e < 8; ++e) { ah[e] = (short)(pw[e] >> 16); al[e] = (short)(pw[e] & 0xffffu); }
      #pragma unroll
      for (int ntl = 0; ntl < 5; ++ntl) {
        acc[mt][ntl] = __builtin_amdgcn_mfma_f32_16x16x32_bf16(ah, bh[ntl], acc[mt][ntl], 0,0,0);
        acc[mt][ntl] = __builtin_amdgcn_mfma_f32_16x16x32_bf16(al, bh[ntl], acc[mt][ntl], 0,0,0);
        acc[mt][ntl] = __builtin_amdgcn_mfma_f32_16x16x32_bf16(ah, bl[ntl], acc[mt][ntl], 0,0,0);
      }
    }
    __syncthreads();
  }
  #pragma unroll
  for (int mt = 0; mt < 4; ++mt)
    #pragma unroll
    for (int ntl = 0; ntl < 5; ++ntl) {
      const int cc = w * 80 + ntl * 16 + r;
      if (cc < 300) {
        uint4 pv;
        unsigned int* pp = (unsigned int*)&pv;
        #pragma unroll
        for (int q = 0; q < 4; ++q) {
          const float v = acc[mt][ntl][q];
          const unsigned short h = f2bf(v);
          pp[q] = ((unsigned int)h << 16) | f2bf(v - bf2f(h));
        }
        *(uint4*)&slab[(size_t)cc * 128 + row0 + mt * 16 + (g << 2)] = pv;
      }
    }
  #pragma unroll
  for (int mt = 0; mt < 4; ++mt) {
    #pragma unroll
    for (int q = 0; q < 4; ++q) {
      float sv = 0.f, dv = 0.f;
      #pragma unroll
      for (int ntl = 0; ntl < 5; ++ntl) {
        const int cc = w * 80 + ntl * 16 + r;
        const float a = acc[mt][ntl][q];
        sv += a * aosl[cc]; dv += a * aodl[cc];
      }
      #pragma unroll
      for (int s = 1; s <= 8; s <<= 1) { sv += __shfl_xor(sv, s); dv += __shfl_xor(dv, s); }
      if (r == 0) {
        const int row_l = mt * 16 + g * 4 + q;
        sred[w][row_l] = sv; dred[w][row_l] = dv;
      }
    }
  }
  __syncthreads();
  if (t < 64) {
    s2g[(size_t)b * 128 + row0 + t] = sred[0][t] + sred[1][t] + sred[2][t] + sred[3][t];
    d2g[(size_t)b * 128 + row0 + t] = dred[0][t] + dred[1][t] + dred[2][t] + dred[3][t];
  }
}

// =============== att2 + elu + log_softmax(features) + mean (rank-1) ===============
__global__ __launch_bounds__(256) void k_att2(
    const unsigned int* __restrict__ buf1, const u64* __restrict__ mg,
    const float* __restrict__ s2g, const float* __restrict__ d2g,
    float* __restrict__ gat)
{
  __shared__ unsigned short Th[16][64][8], Tl[16][64][8];
  __shared__ float sarr[128], darr[128];
  __shared__ u64 mAr[128], mBr[128];
  __shared__ float colsum[304];
  __shared__ float srow[16];
  const int t = threadIdx.x, lane = t & 63, w = t >> 6, r = lane & 15, g = lane >> 4;
  const int b = blockIdx.x;
  const unsigned int* slab = buf1 + (size_t)b * 61440;

  if (t < 128) {
    sarr[t] = s2g[(size_t)b * 128 + t];
    darr[t] = d2g[(size_t)b * 128 + t];
    mAr[t] = mg[((size_t)b * 128 + t) * 2];
    mBr[t] = mg[((size_t)b * 128 + t) * 2 + 1];
  }
  for (int c = t; c < 304; c += 256) colsum[c] = 0.f;
  __syncthreads();
  bf16x8 pah[2][4], pal[2][4];
  float inv2[2];
  #pragma unroll
  for (int mt = 0; mt < 2; ++mt) {
    const int i = w * 32 + mt * 16 + r;
    inv2[mt] = make_att_frags(sarr[i], mAr[i], mBr[i], darr, g, pah[mt], pal[mt]);
  }
  float scq[2][4];
  #pragma unroll
  for (int mt = 0; mt < 2; ++mt)
    #pragma unroll
    for (int q = 0; q < 4; ++q) scq[mt][q] = __shfl(inv2[mt], g * 4 + q);

  float m8[2][4], l8[2][4];
  #pragma unroll
  for (int mt = 0; mt < 2; ++mt)
    #pragma unroll
    for (int q = 0; q < 4; ++q) { m8[mt][q] = -3e38f; l8[mt][q] = 0.f; }

  for (int ch = 0; ch < 5; ++ch) {
    #pragma unroll
    for (int ii = 0; ii < 4; ++ii) {
      const int idx = t + ii * 256;
      const int c = idx & 63, jg = idx >> 6;
      const int gc = ch * 64 + c;
      uint4 p0 = {0,0,0,0}, p1 = {0,0,0,0};
      if (gc < 300) {
        const uint4* src = (const uint4*)&slab[(size_t)gc * 128 + jg * 8];
        p0 = src[0]; p1 = src[1];
      }
      const unsigned int pw[8] = {p0.x,p0.y,p0.z,p0.w,p1.x,p1.y,p1.z,p1.w};
      u16x8 hv, lv;
      #pragma unroll
      for (int e = 0; e < 8; ++e) { hv[e] = (unsigned short)(pw[e] >> 16); lv[e] = (unsigned short)(pw[e] & 0xffffu); }
      const int tile = ((c >> 4) << 2) | (jg >> 2);
      const int li = ((jg & 3) << 4) | (c & 15);
      *(u16x8*)&Th[tile][li][0] = hv;
      *(u16x8*)&Tl[tile][li][0] = lv;
    }
    __syncthreads();
    f32x4 pacc[2][4];
    #pragma unroll
    for (int mt = 0; mt < 2; ++mt)
      #pragma unroll
      for (int nt = 0; nt < 4; ++nt) pacc[mt][nt] = (f32x4){0.f,0.f,0.f,0.f};
    #pragma unroll
    for (int kt = 0; kt < 4; ++kt)
      #pragma unroll
      for (int nt = 0; nt < 4; ++nt) {
        const bf16x8 bh = *(const bf16x8*)&Th[(nt << 2) | kt][lane][0];
        const bf16x8 bl = *(const bf16x8*)&Tl[(nt << 2) | kt][lane][0];
        #pragma unroll
        for (int mt = 0; mt < 2; ++mt) {
          pacc[mt][nt] = __builtin_amdgcn_mfma_f32_16x16x32_bf16(pah[mt][kt], bh, pacc[mt][nt], 0,0,0);
          pacc[mt][nt] = __builtin_amdgcn_mfma_f32_16x16x32_bf16(pal[mt][kt], bh, pacc[mt][nt], 0,0,0);
          pacc[mt][nt] = __builtin_amdgcn_mfma_f32_16x16x32_bf16(pah[mt][kt], bl, pacc[mt][nt], 0,0,0);
        }
      }
    float csA[4] = {0,0,0,0};
    #pragma unroll
    for (int mt = 0; mt < 2; ++mt) {
      float vq[4][4];
      #pragma unroll
      for (int nt = 0; nt < 4; ++nt) {
        const int cc = ch * 64 + nt * 16 + r;
        const bool cv = cc < 300;
        #pragma unroll
        for (int q = 0; q < 4; ++q) {
          float v = pacc[mt][nt][q] * scq[mt][q];
          v = v > 0.f ? v : __expf(v) - 1.f;
          vq[nt][q] = cv ? v : -3e38f;
          csA[nt] += cv ? v : 0.f;
        }
      }
      #pragma unroll
      for (int q = 0; q < 4; ++q) {
        float mx = fmaxf(fmaxf(vq[0][q], vq[1][q]), fmaxf(vq[2][q], vq[3][q]));
        mx = fmaxf(mx, __shfl_xor(mx, 1));
        mx = fmaxf(mx, __shfl_xor(mx, 2));
        mx = fmaxf(mx, __shfl_xor(mx, 4));
        mx = fmaxf(mx, __shfl_xor(mx, 8));
        const float nm = fmaxf(m8[mt][q], mx);
        float ps = __expf(vq[0][q]-nm) + __expf(vq[1][q]-nm) + __expf(vq[2][q]-nm) + __expf(vq[3][q]-nm);
        ps += __shfl_xor(ps, 1); ps += __shfl_xor(ps, 2);
        ps += __shfl_xor(ps, 4); ps += __shfl_xor(ps, 8);
        l8[mt][q] = l8[mt][q] * __expf(m8[mt][q] - nm) + ps;
        m8[mt][q] = nm;
      }
    }
    #pragma unroll
    for (int nt = 0; nt < 4; ++nt) {
      float cs = csA[nt];
      cs += __shfl_xor(cs, 16); cs += __shfl_xor(cs, 32);
      const int cc = ch * 64 + nt * 16 + r;
      if (g == 0 && cc < 300) atomicAdd(&colsum[cc], cs);
    }
    __syncthreads();
  }
  if (r == 0) {
    float sp = 0.f;
    #pragma unroll
    for (int mt = 0; mt < 2; ++mt)
      #pragma unroll
      for (int q = 0; q < 4; ++q) sp += m8[mt][q] + __logf(l8[mt][q]);
    srow[w * 4 + g] = sp;
  }
  __syncthreads();
  float S = 0.f;
  #pragma unroll
  for (int k = 0; k < 16; ++k) S += srow[k];
  for (int c = t; c < 300; c += 256)
    gat[(size_t)b * 300 + c] = (colsum[c] - S) * (1.f / 128.f);
}

// =============== split-K GEMM: P[sk][M][N] = A_chunk @ B_chunk (64x64 tile) ===============
__global__ __launch_bounds__(256) void k_gemm_sk(
    const float* __restrict__ A, const float* __restrict__ B,
    float* __restrict__ P, int M, int K, int N, int kpt)
{
  __shared__ unsigned short Ah[64][40], Al[64][40], Bh[64][40], Bl[64][40];
  const int t = threadIdx.x, lane = t & 63, w = t >> 6, r = lane & 15, g = lane >> 4;
  const int row0 = blockIdx.x * 64, col0 = blockIdx.y * 64;
  const int sk = blockIdx.z;
  const int k0 = sk * kpt * 32;
  const int kend = min(K, k0 + kpt * 32);

  f32x4 acc[4];
  #pragma unroll
  for (int nt = 0; nt < 4; ++nt) acc[nt] = (f32x4){0.f,0.f,0.f,0.f};

  for (int kt = k0; kt < kend; kt += 32) {
    #pragma unroll
    for (int ii = 0; ii < 2; ++ii) {
      const int idx = t + ii * 256, ar = idx >> 3, aq = (idx & 7) * 4, gk = kt + aq;
      const float* ap = &A[(size_t)(row0 + ar) * K + gk];
      float v0 = gk     < kend ? ap[0] : 0.f;
      float v1 = gk + 1 < kend ? ap[1] : 0.f;
      float v2 = gk + 2 < kend ? ap[2] : 0.f;
      float v3 = gk + 3 < kend ? ap[3] : 0.f;
      unsigned short h0=f2bf(v0),h1=f2bf(v1),h2=f2bf(v2),h3=f2bf(v3);
      *(unsigned int*)&Ah[ar][aq]   = h0 | ((unsigned int)h1 << 16);
      *(unsigned int*)&Ah[ar][aq+2] = h2 | ((unsigned int)h3 << 16);
      unsigned short l0=f2bf(v0-bf2f(h0)),l1=f2bf(v1-bf2f(h1)),l2=f2bf(v2-bf2f(h2)),l3=f2bf(v3-bf2f(h3));
      *(unsigned int*)&Al[ar][aq]   = l0 | ((unsigned int)l1 << 16);
      *(unsigned int*)&Al[ar][aq+2] = l2 | ((unsigned int)l3 << 16);
    }
    #pragma unroll
    for (int ii = 0; ii < 4; ++ii) {
      const int idx = t + ii * 256, n = idx & 63, kk = (idx >> 6) * 2;
      const int gn = col0 + n;
      float v0 = (gn < N && kt + kk     < kend) ? B[(size_t)(kt + kk) * N + gn] : 0.f;
      float v1 = (gn < N && kt + kk + 1 < kend) ? B[(size_t)(kt + kk + 1) * N + gn] : 0.f;
      unsigned short h0 = f2bf(v0), h1 = f2bf(v1);
      *(unsigned int*)&Bh[n][kk] = h0 | ((unsigned int)h1 << 16);
      unsigned short l0 = f2bf(v0 - bf2f(h0)), l1 = f2bf(v1 - bf2f(h1));
      *(unsigned int*)&Bl[n][kk] = l0 | ((unsigned int)l1 << 16);
    }
    __syncthreads();
    const bf16x8 ah  = *(const bf16x8*)&Ah[w * 16 + r][g * 8];
    const bf16x8 al2 = *(const bf16x8*)&Al[w * 16 + r][g * 8];
    #pragma unroll
    for (int nt = 0; nt < 4; ++nt) {
      const bf16x8 bh = *(const bf16x8*)&Bh[nt * 16 + r][g * 8];
      const bf16x8 bl = *(const bf16x8*)&Bl[nt * 16 + r][g * 8];
      acc[nt] = __builtin_amdgcn_mfma_f32_16x16x32_bf16(ah,  bh, acc[nt], 0,0,0);
      acc[nt] = __builtin_amdgcn_mfma_f32_16x16x32_bf16(al2, bh, acc[nt], 0,0,0);
      acc[nt] = __builtin_amdgcn_mfma_f32_16x16x32_bf16(ah,  bl, acc[nt], 0,0,0);
    }
    __syncthreads();
  }
  float* Pout = P + (size_t)sk * M * N;
  #pragma unroll
  for (int nt = 0; nt < 4; ++nt) {
    const int cc = col0 + nt * 16 + r;
    if (cc < N) {
      #pragma unroll
      for (int q = 0; q < 4; ++q)
        Pout[(size_t)(row0 + w * 16 + g * 4 + q) * N + cc] = acc[nt][q];
    }
  }
}

// =============== batched pair variant: z<nskA -> problem A, else problem B ===============
// Both problems share M,K,N,kpt. Identical inner loop to k_gemm_sk.
__global__ __launch_bounds__(256) void k_gemm_sk2(
    const float* __restrict__ A1, const float* __restrict__ B1, float* __restrict__ P1o,
    const float* __restrict__ A2, const float* __restrict__ B2, float* __restrict__ P2o,
    int nskA, int M, int K, int N, int kpt)
{
  __shared__ unsigned short Ah[64][40], Al[64][40], Bh[64][40], Bl[64][40];
  const int t = threadIdx.x, lane = t & 63, w = t >> 6, r = lane & 15, g = lane >> 4;
  const int row0 = blockIdx.x * 64, col0 = blockIdx.y * 64;
  const int zz = blockIdx.z;
  const int second = (zz >= nskA);
  const int sk = second ? zz - nskA : zz;
  const float* A = second ? A2 : A1;
  const float* B = second ? B2 : B1;
  float* P = second ? P2o : P1o;
  const int k0 = sk * kpt * 32;
  const int kend = min(K, k0 + kpt * 32);

  f32x4 acc[4];
  #pragma unroll
  for (int nt = 0; nt < 4; ++nt) acc[nt] = (f32x4){0.f,0.f,0.f,0.f};

  for (int kt = k0; kt < kend; kt += 32) {
    #pragma unroll
    for (int ii = 0; ii < 2; ++ii) {
      const int idx = t + ii * 256, ar = idx >> 3, aq = (idx & 7) * 4, gk = kt + aq;
      const float* ap = &A[(size_t)(row0 + ar) * K + gk];
      float v0 = gk     < kend ? ap[0] : 0.f;
      float v1 = gk + 1 < kend ? ap[1] : 0.f;
      float v2 = gk + 2 < kend ? ap[2] : 0.f;
      float v3 = gk + 3 < kend ? ap[3] : 0.f;
      unsigned short h0=f2bf(v0),h1=f2bf(v1),h2=f2bf(v2),h3=f2bf(v3);
      *(unsigned int*)&Ah[ar][aq]   = h0 | ((unsigned int)h1 << 16);
      *(unsigned int*)&Ah[ar][aq+2] = h2 | ((unsigned int)h3 << 16);
      unsigned short l0=f2bf(v0-bf2f(h0)),l1=f2bf(v1-bf2f(h1)),l2=f2bf(v2-bf2f(h2)),l3=f2bf(v3-bf2f(h3));
      *(unsigned int*)&Al[ar][aq]   = l0 | ((unsigned int)l1 << 16);
      *(unsigned int*)&Al[ar][aq+2] = l2 | ((unsigned int)l3 << 16);
    }
    #pragma unroll
    for (int ii = 0; ii < 4; ++ii) {
      const int idx = t + ii * 256, n = idx & 63, kk = (idx >> 6) * 2;
      const int gn = col0 + n;
      float v0 = (gn < N && kt + kk     < kend) ? B[(size_t)(kt + kk) * N + gn] : 0.f;
      float v1 = (gn < N && kt + kk + 1 < kend) ? B[(size_t)(kt + kk + 1) * N + gn] : 0.f;
      unsigned short h0 = f2bf(v0), h1 = f2bf(v1);
      *(unsigned int*)&Bh[n][kk] = h0 | ((unsigned int)h1 << 16);
      unsigned short l0 = f2bf(v0 - bf2f(h0)), l1 = f2bf(v1 - bf2f(h1));
      *(unsigned int*)&Bl[n][kk] = l0 | ((unsigned int)l1 << 16);
    }
    __syncthreads();
    const bf16x8 ah  = *(const bf16x8*)&Ah[w * 16 + r][g * 8];
    const bf16x8 al2 = *(const bf16x8*)&Al[w * 16 + r][g * 8];
    #pragma unroll
    for (int nt = 0; nt < 4; ++nt) {
      const bf16x8 bh = *(const bf16x8*)&Bh[nt * 16 + r][g * 8];
      const bf16x8 bl = *(const bf16x8*)&Bl[nt * 16 + r][g * 8];
      acc[nt] = __builtin_amdgcn_mfma_f32_16x16x32_bf16(ah,  bh, acc[nt], 0,0,0);
      acc[nt] = __builtin_amdgcn_mfma_f32_16x16x32_bf16(al2, bh, acc[nt], 0,0,0);
      acc[nt] = __builtin_amdgcn_mfma_f32_16x16x32_bf16(ah,  bl, acc[nt], 0,0,0);
    }
    __syncthreads();
  }
  float* Pout = P + (size_t)sk * M * N;
  #pragma unroll
  for (int nt = 0; nt < 4; ++nt) {
    const int cc = col0 + nt * 16 + r;
    if (cc < N) {
      #pragma unroll
      for (int q = 0; q < 4; ++q)
        Pout[(size_t)(row0 + w * 16 + g * 4 + q) * N + cc] = acc[nt][q];
    }
  }
}

// =============== split-K reduce + bias + activation ===============
__global__ __launch_bounds__(256) void k_reduce(
    const float* __restrict__ P, const float* __restrict__ bias,
    float* __restrict__ C, int M, int N, int ldc, int nsk, int act)
{
  const int idx = blockIdx.x * 256 + threadIdx.x;
  if (idx >= M * N) return;
  const int row = idx / N, col = idx - row * N;
  float s = bias[col];
  for (int k = 0; k < nsk; ++k) s += P[(size_t)k * M * N + idx];
  if (act) s = fmaxf(s, 0.f);
  C[(size_t)row * ldc + col] = s;
}

// =============== batched pair reduce: first nblkA blocks -> A, rest -> B ===============
__global__ __launch_bounds__(256) void k_reduce2(
    const float* __restrict__ PA, const float* __restrict__ biasA, float* __restrict__ CA,
    const float* __restrict__ PB, const float* __restrict__ biasB, float* __restrict__ CB,
    int M, int N, int ldc, int nsk, int act, int nblkA)
{
  const int second = (blockIdx.x >= nblkA);
  const float* P = second ? PB : PA;
  const float* bias = second ? biasB : biasA;
  float* C = second ? CB : CA;
  const int idx = (second ? blockIdx.x - nblkA : blockIdx.x) * 256 + threadIdx.x;
  if (idx >= M * N) return;
  const int row = idx / N, col = idx - row * N;
  float s = bias[col];
  for (int k = 0; k < nsk; ++k) s += P[(size_t)k * M * N + idx];
  if (act) s = fmaxf(s, 0.f);
  C[(size_t)row * ldc + col] = s;
}

// =============== final GEMV + sigmoid ===============
__global__ __launch_bounds__(512) void k_out(
    const float* __restrict__ z1, const float* __restrict__ w2,
    const float* __restrict__ b2, float* __restrict__ out)
{
  const int t = threadIdx.x, lane = t & 63, w = t >> 6;
  const int b = blockIdx.x * 8 + w;
  float p = 0.f;
  for (int k = lane; k < 300; k += 64) p += z1[(size_t)b * 300 + k] * w2[k];
  p = warp_sum(p);
  if (lane == 0) out[b] = 1.f / (1.f + __expf(-(p + b2[0])));
}

extern "C" void kernel_launch(void* const* d_in, const int* in_sizes, int n_in,
                              void* d_out, int out_size, void* d_ws, size_t ws_size,
                              hipStream_t stream)
{
  const float* x    = (const float*)d_in[0];
  const int*   adj  = (const int*)d_in[1];
  const float* fp   = (const float*)d_in[2];
  const float* Whw  = (const float*)d_in[3];
  const float* asrc = (const float*)d_in[4];
  const float* adst = (const float*)d_in[5];
  const float* Wout = (const float*)d_in[6];
  const float* aos  = (const float*)d_in[7];
  const float* aod  = (const float*)d_in[8];
  const float* fc1w = (const float*)d_in[9];
  const float* fc1b = (const float*)d_in[10];
  const float* fc2w = (const float*)d_in[11];
  const float* fc2b = (const float*)d_in[12];
  const float* fcgw = (const float*)d_in[13];
  const float* fcgb = (const float*)d_in[14];
  const float* fcfw = (const float*)d_in[15];
  const float* fcfb = (const float*)d_in[16];
  const float* f1w  = (const float*)d_in[17];
  const float* f1b  = (const float*)d_in[18];
  const float* f2w  = (const float*)d_in[19];
  const float* f2b  = (const float*)d_in[20];
  float* out = (float*)d_out;

  char* wsb = (char*)d_ws;
  unsigned int* buf1 = (unsigned int*)wsb;
  float* s1g = (float*)(wsb + 125829120);
  float* d1g = (float*)(wsb + 127926272);
  float* s2g = (float*)(wsb + 130023424);
  float* d2g = (float*)(wsb + 130285568);
  u64*   mgb = (u64*)  (wsb + 130547712);
  float* gatp = (float*)(wsb + 131596288);
  float* fpnp = (float*)(wsb + 132210688);
  float* f1buf = (float*)(wsb + 132825088);
  float* zb    = (float*)(wsb + 133873664);
  float* z1b   = (float*)(wsb + 135102464);
  float* P0 = (float*)(wsb + 135716864);
  float* P1 = (float*)(wsb + 142008320);
  float* P2 = (float*)(wsb + 144465920);
  float* P3 = (float*)(wsb + 145694720);
  float* P4 = (float*)(wsb + 146923520);
  unsigned short* Bf1H = (unsigned short*)(wsb + 149381120);
  unsigned short* Bf1L = (unsigned short*)(wsb + 149544960);
  unsigned short* Bf2H = (unsigned short*)(wsb + 149708800);
  unsigned short* Bf2L = (unsigned short*)(wsb + 150016000);

  k_prep1<<<dim3(5, 32), 64, 0, stream>>>(Whw, Bf1H, Bf1L);
  k_prep2<<<dim3(15, 20), 64, 0, stream>>>(Wout, Bf2H, Bf2L);
  k_mask <<<512, 256, 0, stream>>>(adj, mgb);
  // --- GAT chain (unchanged 359 µs baseline) ---
  k_gemm1<<<2048, 512, 0, stream>>>(x, Bf1H, Bf1L, asrc, adst, buf1, s1g, d1g);
  k_att1 <<<4096, 256, 0, stream>>>(buf1, mgb, s1g, d1g);
  k_gemm2<<<1024, 256, 0, stream>>>(buf1, Bf2H, Bf2L, aos, aod, s2g, d2g);
  k_att2 <<<512, 256, 0, stream>>>(buf1, mgb, s2g, d2g, gatp);
  // --- head chain (baseline structure; P2/P3 pairs batched into single launches) ---
  k_gemm_sk<<<dim3(8,8,6), 256, 0, stream>>>(fp, fc1w, P0, 512, 1489, 512, 8);
  k_reduce<<<1024, 256, 0, stream>>>(P0, fc1b, f1buf, 512, 512, 512, 6, 1);
  k_gemm_sk<<<dim3(8,5,4), 256, 0, stream>>>(f1buf, fc2w, P1, 512, 512, 300, 4);
  k_reduce<<<600, 256, 0, stream>>>(P1, fc2b, fpnp, 512, 300, 300, 4, 0);
  k_gemm_sk2<<<dim3(8,5,4), 256, 0, stream>>>(gatp, fcgw, P2, fpnp, fcfw, P3,
                                              2, 512, 300, 300, 5);
  k_reduce2<<<1200, 256, 0, stream>>>(P2, fcgb, zb, P3, fcfb, zb + 300,
                                      512, 300, 600, 2, 1, 600);
  k_gemm_sk<<<dim3(8,5,4), 256, 0, stream>>>(zb, f1w, P4, 512, 600, 300, 5);
  k_reduce<<<600, 256, 0, stream>>>(P4, f1b, z1b, 512, 300, 300, 4, 1);
  k_out<<<64, 512, 0, stream>>>(z1b, f2w, f2b, out);
}

// Round 18
// 330.344 us; speedup vs baseline: 1.2206x; 1.0330x over previous
//
#include <hip/hip_runtime.h>
#include <hip/hip_bf16.h>
#include <math.h>
#include <stdint.h>

#define LRA 0.2f

typedef __attribute__((ext_vector_type(8))) short bf16x8;
typedef __attribute__((ext_vector_type(8))) unsigned short u16x8;
typedef __attribute__((ext_vector_type(4))) float f32x4;
typedef unsigned long long u64;

__device__ __forceinline__ unsigned short f2bf(float v) {
  union { __hip_bfloat16 b; unsigned short u; } c;
  c.b = __float2bfloat16(v);
  return c.u;
}
__device__ __forceinline__ float bf2f(unsigned short h) {
  union { float f; unsigned int u; } a; a.u = ((unsigned int)h) << 16;
  return a.f;
}
__device__ __forceinline__ float warp_sum(float v){
  #pragma unroll
  for (int s = 32; s; s >>= 1) v += __shfl_xor(v, s);
  return v;
}

// =============== setup: adjacency masks + both weight preps in ONE launch ===============
// bid < 512: mask body (per batch). 512..551: prep1 (4 units/block). 552..626: prep2.
__global__ __launch_bounds__(256) void k_setup(
    const int* __restrict__ adj, u64* __restrict__ mg,
    const float* __restrict__ Whw, unsigned short* __restrict__ B1H, unsigned short* __restrict__ B1L,
    const float* __restrict__ W, unsigned short* __restrict__ B2H, unsigned short* __restrict__ B2L)
{
  const int bid = blockIdx.x, t = threadIdx.x;
  if (bid < 512) {
    const int lane = t & 63, w = t >> 6, b = bid;
    const int* adjb = adj + (size_t)b * 128 * 128;
    for (int i = w * 32; i < w * 32 + 32; ++i) {
      u64 b0 = __ballot(adjb[i * 128 + lane] > 0);
      u64 b1 = __ballot(adjb[i * 128 + 64 + lane] > 0);
      if (lane == 0) { mg[((size_t)b * 128 + i) * 2] = b0; mg[((size_t)b * 128 + i) * 2 + 1] = b1; }
    }
  } else if (bid < 552) {
    // prep1: Bcat fragment hi/lo; unit in [0,160): kt=unit>>5, nt=unit&31
    const int unit = (bid - 512) * 4 + (t >> 6);
    const int kt = unit >> 5, nt = unit & 31, l = t & 63;
    const int n = nt * 16 + (l & 15), k0 = kt * 32 + (l >> 4) * 8;
    const int hd = n / 60, j = n - hd * 60;
    uint4 hv, lv;
    unsigned int* hp = (unsigned int*)&hv;
    unsigned int* lp = (unsigned int*)&lv;
    #pragma unroll
    for (int p = 0; p < 4; ++p) {
      unsigned short hh[2], ll[2];
      #pragma unroll
      for (int e = 0; e < 2; ++e) {
        const int k = k0 + p * 2 + e;
        const float v = (n < 480 && k < 133) ? Whw[((size_t)hd * 133 + k) * 60 + j] : 0.f;
        const unsigned short h = f2bf(v);
        hh[e] = h; ll[e] = f2bf(v - bf2f(h));
      }
      hp[p] = hh[0] | ((unsigned int)hh[1] << 16);
      lp[p] = ll[0] | ((unsigned int)ll[1] << 16);
    }
    const size_t off = (((size_t)(kt * 32 + nt)) * 64 + l) * 8;
    *(uint4*)&B1H[off] = hv;
    *(uint4*)&B1L[off] = lv;
  } else {
    // prep2: Wout fragment hi/lo; unit in [0,300): kt=unit/20, nt=unit%20
    const int unit = (bid - 552) * 4 + (t >> 6);
    const int kt = unit / 20, nt = unit - kt * 20, l = t & 63;
    const int n = nt * 16 + (l & 15), k0 = kt * 32 + (l >> 4) * 8;
    uint4 hv, lv;
    unsigned int* hp = (unsigned int*)&hv;
    unsigned int* lp = (unsigned int*)&lv;
    #pragma unroll
    for (int p = 0; p < 4; ++p) {
      unsigned short hh[2], ll[2];
      #pragma unroll
      for (int e = 0; e < 2; ++e) {
        const int k = k0 + p * 2 + e;
        const float v = (n < 300 && k < 480) ? W[(size_t)k * 300 + n] : 0.f;
        const unsigned short h = f2bf(v);
        hh[e] = h; ll[e] = f2bf(v - bf2f(h));
      }
      hp[p] = hh[0] | ((unsigned int)hh[1] << 16);
      lp[p] = ll[0] | ((unsigned int)ll[1] << 16);
    }
    const size_t off = (((size_t)(kt * 20 + nt)) * 64 + l) * 8;
    *(uint4*)&B2H[off] = hv;
    *(uint4*)&B2L[off] = lv;
  }
}

// =============== GEMM1: Wh = x @ Bcat; 4 row-parts per batch ===============
__global__ __launch_bounds__(512) void k_gemm1(
    const float* __restrict__ x,
    const unsigned short* __restrict__ BH, const unsigned short* __restrict__ BL,
    const float* __restrict__ asrc, const float* __restrict__ adst,
    unsigned int* __restrict__ buf1, float* __restrict__ s1g, float* __restrict__ d1g)
{
  __shared__ unsigned int Apk[32][32];
  __shared__ float asl[512], adl[512];
  __shared__ float sp0[8][32], sp1[8][32], dp0[8][32], dp1[8][32];
  const int t = threadIdx.x, lane = t & 63, w = t >> 6, r = lane & 15, g = lane >> 4;
  const int b = blockIdx.x >> 2, p = blockIdx.x & 3;
  const int row0 = p * 32;
  const float* xb = x + (size_t)b * 128 * 133;
  unsigned int* slab = buf1 + (size_t)b * 61440;

  asl[t] = (t < 480) ? asrc[t] : 0.f;
  adl[t] = (t < 480) ? adst[t] : 0.f;

  f32x4 acc[2][4];
  #pragma unroll
  for (int mt = 0; mt < 2; ++mt)
    #pragma unroll
    for (int ntl = 0; ntl < 4; ++ntl) acc[mt][ntl] = (f32x4){0.f,0.f,0.f,0.f};

  for (int kt = 0; kt < 5; ++kt) {
    if (t < 256) {
      const int row_l = t >> 3, sl = t & 7;
      const int k0 = kt * 32 + sl * 4;
      uint4 pk;
      unsigned int* pp = (unsigned int*)&pk;
      #pragma unroll
      for (int e = 0; e < 4; ++e) {
        const int k = k0 + e;
        const float v = (k < 133) ? xb[(size_t)(row0 + row_l) * 133 + k] : 0.f;
        const unsigned short h = f2bf(v);
        pp[e] = ((unsigned int)h << 16) | f2bf(v - bf2f(h));
      }
      *(uint4*)&Apk[row_l][((sl ^ (row_l & 7)) << 2)] = pk;
    }
    bf16x8 bh[4], bl[4];
    #pragma unroll
    for (int ntl = 0; ntl < 4; ++ntl) {
      const int nt = w * 4 + ntl;
      const size_t off = (((size_t)(kt * 32 + nt)) * 64 + lane) * 8;
      bh[ntl] = *(const bf16x8*)&BH[off];
      bl[ntl] = *(const bf16x8*)&BL[off];
    }
    __syncthreads();
    #pragma unroll
    for (int mt = 0; mt < 2; ++mt) {
      const int row_l = mt * 16 + r, key = r & 7;
      const uint4 p0 = *(const uint4*)&Apk[row_l][(((2*g)   ^ key) << 2)];
      const uint4 p1 = *(const uint4*)&Apk[row_l][(((2*g+1) ^ key) << 2)];
      const unsigned int pw[8] = {p0.x,p0.y,p0.z,p0.w,p1.x,p1.y,p1.z,p1.w};
      bf16x8 ah, al;
      #pragma unroll
      for (int e = 0; e < 8; ++e) { ah[e] = (short)(pw[e] >> 16); al[e] = (short)(pw[e] & 0xffffu); }
      #pragma unroll
      for (int ntl = 0; ntl < 4; ++ntl) {
        acc[mt][ntl] = __builtin_amdgcn_mfma_f32_16x16x32_bf16(ah, bh[ntl], acc[mt][ntl], 0,0,0);
        acc[mt][ntl] = __builtin_amdgcn_mfma_f32_16x16x32_bf16(al, bh[ntl], acc[mt][ntl], 0,0,0);
        acc[mt][ntl] = __builtin_amdgcn_mfma_f32_16x16x32_bf16(ah, bl[ntl], acc[mt][ntl], 0,0,0);
      }
    }
    __syncthreads();
  }
  #pragma unroll
  for (int mt = 0; mt < 2; ++mt)
    #pragma unroll
    for (int ntl = 0; ntl < 4; ++ntl) {
      const int cc = (w * 4 + ntl) * 16 + r;
      if (cc < 480) {
        const int hd = cc / 60, cl = cc - hd * 60;
        uint4 pv;
        unsigned int* pp = (unsigned int*)&pv;
        #pragma unroll
        for (int q = 0; q < 4; ++q) {
          const float v = acc[mt][ntl][q];
          const unsigned short h = f2bf(v);
          pp[q] = ((unsigned int)h << 16) | f2bf(v - bf2f(h));
        }
        *(uint4*)&slab[(size_t)hd * 7680 + (size_t)cl * 128 + row0 + mt * 16 + (g << 2)] = pv;
      }
    }
  const int thr0 = 60 - 4 * w;
  #pragma unroll
  for (int mt = 0; mt < 2; ++mt) {
    #pragma unroll
    for (int q = 0; q < 4; ++q) {
      float s0 = 0.f, s1 = 0.f, d0 = 0.f, d1 = 0.f;
      #pragma unroll
      for (int ntl = 0; ntl < 4; ++ntl) {
        const int loc = ntl * 16 + r;
        const int cc = w * 64 + loc;
        const float a = acc[mt][ntl][q];
        const float as = asl[cc], ad = adl[cc];
        if (loc < thr0) { s0 += a * as; d0 += a * ad; }
        else            { s1 += a * as; d1 += a * ad; }
      }
      #pragma unroll
      for (int s = 1; s <= 8; s <<= 1) {
        s0 += __shfl_xor(s0, s); s1 += __shfl_xor(s1, s);
        d0 += __shfl_xor(d0, s); d1 += __shfl_xor(d1, s);
      }
      if (r == 0) {
        const int row_l = mt * 16 + g * 4 + q;
        sp0[w][row_l] = s0; sp1[w][row_l] = s1;
        dp0[w][row_l] = d0; dp1[w][row_l] = d1;
      }
    }
  }
  __syncthreads();
  if (t < 256) {
    const int hd = t >> 5, row_l = t & 31;
    s1g[((size_t)b * 8 + hd) * 128 + row0 + row_l] = sp0[hd][row_l] + (hd > 0 ? sp1[hd-1][row_l] : 0.f);
    d1g[((size_t)b * 8 + hd) * 128 + row0 + row_l] = dp0[hd][row_l] + (hd > 0 ? dp1[hd-1][row_l] : 0.f);
  }
}

// ===== merged attention-fragment generator (shared by att1/att2) =====
__device__ __forceinline__ float make_att_frags(
    const float si, const u64 ma, const u64 mb2, const float* darr,
    const int g, bf16x8* pah, bf16x8* pal)
{
  const unsigned int mby[4] = {
    (unsigned int)(ma  >> (g * 8)) & 0xffu,
    (unsigned int)(ma  >> (32 + g * 8)) & 0xffu,
    (unsigned int)(mb2 >> (g * 8)) & 0xffu,
    (unsigned int)(mb2 >> (32 + g * 8)) & 0xffu };
  float ev[4][8];
  float mx = -3e38f;
  #pragma unroll
  for (int kt = 0; kt < 4; ++kt)
    #pragma unroll
    for (int e = 0; e < 8; ++e) {
      const int j = ((kt & 1) * 32) + ((kt >> 1) * 64) + g * 8 + e;
      float v = si + darr[j];
      v = fmaxf(v, LRA * v);
      const float vv = (mby[((kt & 1) << 1) | (kt >> 1)] & (1u << e)) ? v : -3e38f;
      ev[kt][e] = vv;
      mx = fmaxf(mx, vv);
    }
  mx = fmaxf(mx, __shfl_xor(mx, 16));
  mx = fmaxf(mx, __shfl_xor(mx, 32));
  float sum = 0.f;
  #pragma unroll
  for (int kt = 0; kt < 4; ++kt)
    #pragma unroll
    for (int e = 0; e < 8; ++e) {
      const float p = (ev[kt][e] > -1e37f) ? __expf(ev[kt][e] - mx) : 0.f;
      ev[kt][e] = p;
      sum += p;
    }
  sum += __shfl_xor(sum, 16);
  sum += __shfl_xor(sum, 32);
  #pragma unroll
  for (int kt = 0; kt < 4; ++kt) {
    const int ks = ((kt & 1) << 1) | (kt >> 1);
    union { unsigned int u[4]; bf16x8 v; } hw, lw;
    #pragma unroll
    for (int p2 = 0; p2 < 4; ++p2) {
      const float p0 = ev[ks][2 * p2], p1 = ev[ks][2 * p2 + 1];
      const unsigned short h0 = f2bf(p0), h1 = f2bf(p1);
      hw.u[p2] = h0 | ((unsigned int)h1 << 16);
      lw.u[p2] = f2bf(p0 - bf2f(h0)) | ((unsigned int)f2bf(p1 - bf2f(h1)) << 16);
    }
    pah[kt] = hw.v;
    pal[kt] = lw.v;
  }
  return 1.f / sum;
}

// =============== att1: per (b,head); h = elu(att@Wh) in-place ===============
__global__ __launch_bounds__(256) void k_att1(
    unsigned int* __restrict__ buf1, const u64* __restrict__ mg,
    const float* __restrict__ s1g, const float* __restrict__ d1g)
{
  __shared__ unsigned short Th[16][64][8], Tl[16][64][8];
  __shared__ float sarr[128], darr[128];
  __shared__ u64 mAr[128], mBr[128];
  const int t = threadIdx.x, lane = t & 63, w = t >> 6, r = lane & 15, g = lane >> 4;
  const int bid = blockIdx.x;
  const int lb = ((bid & 7) << 9) | (bid >> 3);
  const int b = lb >> 3, hd = lb & 7;
  const size_t sl = (size_t)b * 8 + hd;
  unsigned int* slab = buf1 + sl * 7680;

  if (t < 128) {
    sarr[t] = s1g[sl * 128 + t];
    darr[t] = d1g[sl * 128 + t];
    mAr[t] = mg[((size_t)b * 128 + t) * 2];
    mBr[t] = mg[((size_t)b * 128 + t) * 2 + 1];
  }
  #pragma unroll
  for (int ii = 0; ii < 4; ++ii) {
    const int idx = t + ii * 256;
    const int c = idx & 63, jg = idx >> 6;
    uint4 p0 = {0,0,0,0}, p1 = {0,0,0,0};
    if (c < 60) {
      const uint4* src = (const uint4*)&slab[(size_t)c * 128 + jg * 8];
      p0 = src[0]; p1 = src[1];
    }
    const unsigned int pw[8] = {p0.x,p0.y,p0.z,p0.w,p1.x,p1.y,p1.z,p1.w};
    u16x8 hv, lv;
    #pragma unroll
    for (int e = 0; e < 8; ++e) { hv[e] = (unsigned short)(pw[e] >> 16); lv[e] = (unsigned short)(pw[e] & 0xffffu); }
    const int tile = ((c >> 4) << 2) | (jg >> 2);
    const int li = ((jg & 3) << 4) | (c & 15);
    *(u16x8*)&Th[tile][li][0] = hv;
    *(u16x8*)&Tl[tile][li][0] = lv;
  }
  __syncthreads();
  bf16x8 pah[2][4], pal[2][4];
  float inv2[2];
  #pragma unroll
  for (int mt = 0; mt < 2; ++mt) {
    const int i = w * 32 + mt * 16 + r;
    inv2[mt] = make_att_frags(sarr[i], mAr[i], mBr[i], darr, g, pah[mt], pal[mt]);
  }
  f32x4 acc[2][4];
  #pragma unroll
  for (int mt = 0; mt < 2; ++mt)
    #pragma unroll
    for (int nt = 0; nt < 4; ++nt) acc[mt][nt] = (f32x4){0.f,0.f,0.f,0.f};
  #pragma unroll
  for (int kt = 0; kt < 4; ++kt)
    #pragma unroll
    for (int nt = 0; nt < 4; ++nt) {
      const bf16x8 bh = *(const bf16x8*)&Th[(nt << 2) | kt][lane][0];
      const bf16x8 bl = *(const bf16x8*)&Tl[(nt << 2) | kt][lane][0];
      #pragma unroll
      for (int mt = 0; mt < 2; ++mt) {
        acc[mt][nt] = __builtin_amdgcn_mfma_f32_16x16x32_bf16(pah[mt][kt], bh, acc[mt][nt], 0,0,0);
        acc[mt][nt] = __builtin_amdgcn_mfma_f32_16x16x32_bf16(pal[mt][kt], bh, acc[mt][nt], 0,0,0);
        acc[mt][nt] = __builtin_amdgcn_mfma_f32_16x16x32_bf16(pah[mt][kt], bl, acc[mt][nt], 0,0,0);
      }
    }
  #pragma unroll
  for (int mt = 0; mt < 2; ++mt) {
    float sc[4];
    #pragma unroll
    for (int q = 0; q < 4; ++q) sc[q] = __shfl(inv2[mt], g * 4 + q);
    #pragma unroll
    for (int nt = 0; nt < 4; ++nt) {
      const int cc = nt * 16 + r;
      if (cc < 60) {
        #pragma unroll
        for (int q = 0; q < 4; ++q) {
          const int row = w * 32 + mt * 16 + g * 4 + q;
          float v = acc[mt][nt][q] * sc[q];
          v = v > 0.f ? v : __expf(v) - 1.f;
          const unsigned short h = f2bf(v), l = f2bf(v - bf2f(h));
          slab[(size_t)row * 60 + cc] = ((unsigned int)h << 16) | l;
        }
      }
    }
  }
}

// =============== GEMM2: Wo = h @ W_out; 2 row-parts (64 rows) per batch ===============
__global__ __launch_bounds__(256, 3) void k_gemm2(
    unsigned int* __restrict__ buf1,
    const unsigned short* __restrict__ BH, const unsigned short* __restrict__ BL,
    const float* __restrict__ aos, const float* __restrict__ aod,
    float* __restrict__ s2g, float* __restrict__ d2g)
{
  __shared__ unsigned int Apk[64][32];
  __shared__ float aosl[320], aodl[320];
  __shared__ float sred[4][64], dred[4][64];
  const int t = threadIdx.x, lane = t & 63, w = t >> 6, r = lane & 15, g = lane >> 4;
  const int b = blockIdx.x >> 1, p = blockIdx.x & 1;
  const int row0 = p * 64;
  unsigned int* slab = buf1 + (size_t)b * 61440;
  if (t < 320) { aosl[t] = t < 300 ? aos[t] : 0.f; aodl[t] = t < 300 ? aod[t] : 0.f; }

  f32x4 acc[4][5];
  #pragma unroll
  for (int mt = 0; mt < 4; ++mt)
    #pragma unroll
    for (int ntl = 0; ntl < 5; ++ntl) acc[mt][ntl] = (f32x4){0.f,0.f,0.f,0.f};

  for (int kt = 0; kt < 15; ++kt) {
    #pragma unroll
    for (int i = 0; i < 2; ++i) {
      const int idx = t + i * 256, row_l = idx >> 3, sl = idx & 7;
      const int k0 = kt * 32 + sl * 4;
      const int hd = k0 / 60, c = k0 - hd * 60;
      const uint4 v = *(const uint4*)&slab[(size_t)hd * 7680 + (size_t)(row0 + row_l) * 60 + c];
      *(uint4*)&Apk[row_l][((sl ^ (row_l & 7)) << 2)] = v;
    }
    bf16x8 bh[5], bl[5];
    #pragma unroll
    for (int ntl = 0; ntl < 5; ++ntl) {
      const int nt = w * 5 + ntl;
      const size_t off = (((size_t)(kt * 20 + nt)) * 64 + lane) * 8;
      bh[ntl] = *(const bf16x8*)&BH[off];
      bl[ntl] = *(const bf16x8*)&BL[off];
    }
    __syncthreads();
    #pragma unroll
    for (int mt = 0; mt < 4; ++mt) {
      const int row_l = mt * 16 + r, key = r & 7;
      const uint4 p0 = *(const uint4*)&Apk[row_l][(((2*g)   ^ key) << 2)];
      const uint4 p1 = *(const uint4*)&Apk[row_l][(((2*g+1) ^ key) << 2)];
      const unsigned int pw[8] = {p0.x,p0.y,p0.z,p0.w,p1.x,p1.y,p1.z,p1.w};
      bf16x8 ah, al;
      #pragma unroll
      for (int e = 0; e < 8; ++e) { ah[e] = (short)(pw[e] >> 16); al[e] = (short)(pw[e] & 0xffffu); }
      #pragma unroll
      for (int ntl = 0; ntl < 5; ++ntl) {
        acc[mt][ntl] = __builtin_amdgcn_mfma_f32_16x16x32_bf16(ah, bh[ntl], acc[mt][ntl], 0,0,0);
        acc[mt][ntl] = __builtin_amdgcn_mfma_f32_16x16x32_bf16(al, bh[ntl], acc[mt][ntl], 0,0,0);
        acc[mt][ntl] = __builtin_amdgcn_mfma_f32_16x16x32_bf16(ah, bl[ntl], acc[mt][ntl], 0,0,0);
      }
    }
    __syncthreads();
  }
  #pragma unroll
  for (int mt = 0; mt < 4; ++mt)
    #pragma unroll
    for (int ntl = 0; ntl < 5; ++ntl) {
      const int cc = w * 80 + ntl * 16 + r;
      if (cc < 300) {
        uint4 pv;
        unsigned int* pp = (unsigned int*)&pv;
        #pragma unroll
        for (int q = 0; q < 4; ++q) {
          const float v = acc[mt][ntl][q];
          const unsigned short h = f2bf(v);
          pp[q] = ((unsigned int)h << 16) | f2bf(v - bf2f(h));
        }
        *(uint4*)&slab[(size_t)cc * 128 + row0 + mt * 16 + (g << 2)] = pv;
      }
    }
  #pragma unroll
  for (int mt = 0; mt < 4; ++mt) {
    #pragma unroll
    for (int q = 0; q < 4; ++q) {
      float sv = 0.f, dv = 0.f;
      #pragma unroll
      for (int ntl = 0; ntl < 5; ++ntl) {
        const int cc = w * 80 + ntl * 16 + r;
        const float a = acc[mt][ntl][q];
        sv += a * aosl[cc]; dv += a * aodl[cc];
      }
      #pragma unroll
      for (int s = 1; s <= 8; s <<= 1) { sv += __shfl_xor(sv, s); dv += __shfl_xor(dv, s); }
      if (r == 0) {
        const int row_l = mt * 16 + g * 4 + q;
        sred[w][row_l] = sv; dred[w][row_l] = dv;
      }
    }
  }
  __syncthreads();
  if (t < 64) {
    s2g[(size_t)b * 128 + row0 + t] = sred[0][t] + sred[1][t] + sred[2][t] + sred[3][t];
    d2g[(size_t)b * 128 + row0 + t] = dred[0][t] + dred[1][t] + dred[2][t] + dred[3][t];
  }
}

// =============== BATCHED: att2 (bid<512) + fc1 split-K GEMM (bid>=512) ===============
// att2 body verbatim (carved shared); fc1: P0 = fp @ fc1w, M=512,K=1489,N=512,kpt=8,
// grid decode of original dim3(8,8,6): idx=bid-512; row0=(idx&7)*64, col0=((idx>>3)&7)*64, sk=idx>>6.
__global__ __launch_bounds__(256) void k_att2fc1(
    const unsigned int* __restrict__ buf1, const u64* __restrict__ mg,
    const float* __restrict__ s2g, const float* __restrict__ d2g,
    float* __restrict__ gat,
    const float* __restrict__ fp, const float* __restrict__ fc1w, float* __restrict__ P0)
{
  __shared__ __align__(16) char SMEM[37120];
  const int t = threadIdx.x, lane = t & 63, w = t >> 6, r = lane & 15, g = lane >> 4;
  if (blockIdx.x < 512) {
    // ---- att2 body (verbatim, shared carved from SMEM) ----
    unsigned short* ThB = (unsigned short*)SMEM;        // [16][64][8]
    unsigned short* TlB = ThB + 8192;
    float* sarr = (float*)(SMEM + 32768);
    float* darr = sarr + 128;
    u64* mAr = (u64*)(SMEM + 33792);
    u64* mBr = mAr + 128;
    float* colsum = (float*)(SMEM + 35840);
    float* srow = colsum + 304;
    const int b = blockIdx.x;
    const unsigned int* slab = buf1 + (size_t)b * 61440;

    if (t < 128) {
      sarr[t] = s2g[(size_t)b * 128 + t];
      darr[t] = d2g[(size_t)b * 128 + t];
      mAr[t] = mg[((size_t)b * 128 + t) * 2];
      mBr[t] = mg[((size_t)b * 128 + t) * 2 + 1];
    }
    for (int c = t; c < 304; c += 256) colsum[c] = 0.f;
    __syncthreads();
    bf16x8 pah[2][4], pal[2][4];
    float inv2[2];
    #pragma unroll
    for (int mt = 0; mt < 2; ++mt) {
      const int i = w * 32 + mt * 16 + r;
      inv2[mt] = make_att_frags(sarr[i], mAr[i], mBr[i], darr, g, pah[mt], pal[mt]);
    }
    float scq[2][4];
    #pragma unroll
    for (int mt = 0; mt < 2; ++mt)
      #pragma unroll
      for (int q = 0; q < 4; ++q) scq[mt][q] = __shfl(inv2[mt], g * 4 + q);

    float m8[2][4], l8[2][4];
    #pragma unroll
    for (int mt = 0; mt < 2; ++mt)
      #pragma unroll
      for (int q = 0; q < 4; ++q) { m8[mt][q] = -3e38f; l8[mt][q] = 0.f; }

    for (int ch = 0; ch < 5; ++ch) {
      #pragma unroll
      for (int ii = 0; ii < 4; ++ii) {
        const int idx = t + ii * 256;
        const int c = idx & 63, jg = idx >> 6;
        const int gc = ch * 64 + c;
        uint4 p0 = {0,0,0,0}, p1 = {0,0,0,0};
        if (gc < 300) {
          const uint4* src = (const uint4*)&slab[(size_t)gc * 128 + jg * 8];
          p0 = src[0]; p1 = src[1];
        }
        const unsigned int pw[8] = {p0.x,p0.y,p0.z,p0.w,p1.x,p1.y,p1.z,p1.w};
        u16x8 hv, lv;
        #pragma unroll
        for (int e = 0; e < 8; ++e) { hv[e] = (unsigned short)(pw[e] >> 16); lv[e] = (unsigned short)(pw[e] & 0xffffu); }
        const int tile = ((c >> 4) << 2) | (jg >> 2);
        const int li = ((jg & 3) << 4) | (c & 15);
        *(u16x8*)&ThB[((size_t)tile * 64 + li) * 8] = hv;
        *(u16x8*)&TlB[((size_t)tile * 64 + li) * 8] = lv;
      }
      __syncthreads();
      f32x4 pacc[2][4];
      #pragma unroll
      for (int mt = 0; mt < 2; ++mt)
        #pragma unroll
        for (int nt = 0; nt < 4; ++nt) pacc[mt][nt] = (f32x4){0.f,0.f,0.f,0.f};
      #pragma unroll
      for (int kt = 0; kt < 4; ++kt)
        #pragma unroll
        for (int nt = 0; nt < 4; ++nt) {
          const bf16x8 bh = *(const bf16x8*)&ThB[(((nt << 2) | kt) * 64 + lane) * 8];
          const bf16x8 bl = *(const bf16x8*)&TlB[(((nt << 2) | kt) * 64 + lane) * 8];
          #pragma unroll
          for (int mt = 0; mt < 2; ++mt) {
            pacc[mt][nt] = __builtin_amdgcn_mfma_f32_16x16x32_bf16(pah[mt][kt], bh, pacc[mt][nt], 0,0,0);
            pacc[mt][nt] = __builtin_amdgcn_mfma_f32_16x16x32_bf16(pal[mt][kt], bh, pacc[mt][nt], 0,0,0);
            pacc[mt][nt] = __builtin_amdgcn_mfma_f32_16x16x32_bf16(pah[mt][kt], bl, pacc[mt][nt], 0,0,0);
          }
        }
      float csA[4] = {0,0,0,0};
      #pragma unroll
      for (int mt = 0; mt < 2; ++mt) {
        float vq[4][4];
        #pragma unroll
        for (int nt = 0; nt < 4; ++nt) {
          const int cc = ch * 64 + nt * 16 + r;
          const bool cv = cc < 300;
          #pragma unroll
          for (int q = 0; q < 4; ++q) {
            float v = pacc[mt][nt][q] * scq[mt][q];
            v = v > 0.f ? v : __expf(v) - 1.f;
            vq[nt][q] = cv ? v : -3e38f;
            csA[nt] += cv ? v : 0.f;
          }
        }
        #pragma unroll
        for (int q = 0; q < 4; ++q) {
          float mx = fmaxf(fmaxf(vq[0][q], vq[1][q]), fmaxf(vq[2][q], vq[3][q]));
          mx = fmaxf(mx, __shfl_xor(mx, 1));
          mx = fmaxf(mx, __shfl_xor(mx, 2));
          mx = fmaxf(mx, __shfl_xor(mx, 4));
          mx = fmaxf(mx, __shfl_xor(mx, 8));
          const float nm = fmaxf(m8[mt][q], mx);
          float ps = __expf(vq[0][q]-nm) + __expf(vq[1][q]-nm) + __expf(vq[2][q]-nm) + __expf(vq[3][q]-nm);
          ps += __shfl_xor(ps, 1); ps += __shfl_xor(ps, 2);
          ps += __shfl_xor(ps, 4); ps += __shfl_xor(ps, 8);
          l8[mt][q] = l8[mt][q] * __expf(m8[mt][q] - nm) + ps;
          m8[mt][q] = nm;
        }
      }
      #pragma unroll
      for (int nt = 0; nt < 4; ++nt) {
        float cs = csA[nt];
        cs += __shfl_xor(cs, 16); cs += __shfl_xor(cs, 32);
        const int cc = ch * 64 + nt * 16 + r;
        if (g == 0 && cc < 300) atomicAdd(&colsum[cc], cs);
      }
      __syncthreads();
    }
    if (r == 0) {
      float sp = 0.f;
      #pragma unroll
      for (int mt = 0; mt < 2; ++mt)
        #pragma unroll
        for (int q = 0; q < 4; ++q) sp += m8[mt][q] + __logf(l8[mt][q]);
      srow[w * 4 + g] = sp;
    }
    __syncthreads();
    float S = 0.f;
    #pragma unroll
    for (int k = 0; k < 16; ++k) S += srow[k];
    for (int c = t; c < 300; c += 256)
      gat[(size_t)b * 300 + c] = (colsum[c] - S) * (1.f / 128.f);
  } else {
    // ---- fc1 split-K GEMM body (verbatim k_gemm_sk, M=512 K=1489 N=512 kpt=8) ----
    unsigned short* Ah = (unsigned short*)SMEM;    // [64][40]
    unsigned short* Al = Ah + 2560;
    unsigned short* Bh = Ah + 5120;
    unsigned short* Bl = Ah + 7680;
    const int idx0 = blockIdx.x - 512;
    const int row0 = (idx0 & 7) * 64, col0 = ((idx0 >> 3) & 7) * 64;
    const int sk = idx0 >> 6;
    const int M = 512, K = 1489, N = 512, kpt = 8;
    const float* A = fp;
    const float* B = fc1w;
    const int k0 = sk * kpt * 32;
    const int kend = min(K, k0 + kpt * 32);

    f32x4 acc[4];
    #pragma unroll
    for (int nt = 0; nt < 4; ++nt) acc[nt] = (f32x4){0.f,0.f,0.f,0.f};

    for (int kt = k0; kt < kend; kt += 32) {
      #pragma unroll
      for (int ii = 0; ii < 2; ++ii) {
        const int idx = t + ii * 256, ar = idx >> 3, aq = (idx & 7) * 4, gk = kt + aq;
        const float* ap = &A[(size_t)(row0 + ar) * K + gk];
        float v0 = gk     < kend ? ap[0] : 0.f;
        float v1 = gk + 1 < kend ? ap[1] : 0.f;
        float v2 = gk + 2 < kend ? ap[2] : 0.f;
        float v3 = gk + 3 < kend ? ap[3] : 0.f;
        unsigned short h0=f2bf(v0),h1=f2bf(v1),h2=f2bf(v2),h3=f2bf(v3);
        *(unsigned int*)&Ah[ar * 40 + aq]     = h0 | ((unsigned int)h1 << 16);
        *(unsigned int*)&Ah[ar * 40 + aq + 2] = h2 | ((unsigned int)h3 << 16);
        unsigned short l0=f2bf(v0-bf2f(h0)),l1=f2bf(v1-bf2f(h1)),l2=f2bf(v2-bf2f(h2)),l3=f2bf(v3-bf2f(h3));
        *(unsigned int*)&Al[ar * 40 + aq]     = l0 | ((unsigned int)l1 << 16);
        *(unsigned int*)&Al[ar * 40 + aq + 2] = l2 | ((unsigned int)l3 << 16);
      }
      #pragma unroll
      for (int ii = 0; ii < 4; ++ii) {
        const int idx = t + ii * 256, n = idx & 63, kk = (idx >> 6) * 2;
        const int gn = col0 + n;
        float v0 = (gn < N && kt + kk     < kend) ? B[(size_t)(kt + kk) * N + gn] : 0.f;
        float v1 = (gn < N && kt + kk + 1 < kend) ? B[(size_t)(kt + kk + 1) * N + gn] : 0.f;
        unsigned short h0 = f2bf(v0), h1 = f2bf(v1);
        *(unsigned int*)&Bh[n * 40 + kk] = h0 | ((unsigned int)h1 << 16);
        unsigned short l0 = f2bf(v0 - bf2f(h0)), l1 = f2bf(v1 - bf2f(h1));
        *(unsigned int*)&Bl[n * 40 + kk] = l0 | ((unsigned int)l1 << 16);
      }
      __syncthreads();
      const bf16x8 ah  = *(const bf16x8*)&Ah[(w * 16 + r) * 40 + g * 8];
      const bf16x8 al2 = *(const bf16x8*)&Al[(w * 16 + r) * 40 + g * 8];
      #pragma unroll
      for (int nt = 0; nt < 4; ++nt) {
        const bf16x8 bh = *(const bf16x8*)&Bh[(nt * 16 + r) * 40 + g * 8];
        const bf16x8 bl = *(const bf16x8*)&Bl[(nt * 16 + r) * 40 + g * 8];
        acc[nt] = __builtin_amdgcn_mfma_f32_16x16x32_bf16(ah,  bh, acc[nt], 0,0,0);
        acc[nt] = __builtin_amdgcn_mfma_f32_16x16x32_bf16(al2, bh, acc[nt], 0,0,0);
        acc[nt] = __builtin_amdgcn_mfma_f32_16x16x32_bf16(ah,  bl, acc[nt], 0,0,0);
      }
      __syncthreads();
    }
    float* Pout = P0 + (size_t)sk * M * N;
    #pragma unroll
    for (int nt = 0; nt < 4; ++nt) {
      const int cc = col0 + nt * 16 + r;
      if (cc < N) {
        #pragma unroll
        for (int q = 0; q < 4; ++q)
          Pout[(size_t)(row0 + w * 16 + g * 4 + q) * N + cc] = acc[nt][q];
      }
    }
  }
}

// =============== split-K GEMM: P[sk][M][N] = A_chunk @ B_chunk (64x64 tile) ===============
__global__ __launch_bounds__(256) void k_gemm_sk(
    const float* __restrict__ A, const float* __restrict__ B,
    float* __restrict__ P, int M, int K, int N, int kpt)
{
  __shared__ unsigned short Ah[64][40], Al[64][40], Bh[64][40], Bl[64][40];
  const int t = threadIdx.x, lane = t & 63, w = t >> 6, r = lane & 15, g = lane >> 4;
  const int row0 = blockIdx.x * 64, col0 = blockIdx.y * 64;
  const int sk = blockIdx.z;
  const int k0 = sk * kpt * 32;
  const int kend = min(K, k0 + kpt * 32);

  f32x4 acc[4];
  #pragma unroll
  for (int nt = 0; nt < 4; ++nt) acc[nt] = (f32x4){0.f,0.f,0.f,0.f};

  for (int kt = k0; kt < kend; kt += 32) {
    #pragma unroll
    for (int ii = 0; ii < 2; ++ii) {
      const int idx = t + ii * 256, ar = idx >> 3, aq = (idx & 7) * 4, gk = kt + aq;
      const float* ap = &A[(size_t)(row0 + ar) * K + gk];
      float v0 = gk     < kend ? ap[0] : 0.f;
      float v1 = gk + 1 < kend ? ap[1] : 0.f;
      float v2 = gk + 2 < kend ? ap[2] : 0.f;
      float v3 = gk + 3 < kend ? ap[3] : 0.f;
      unsigned short h0=f2bf(v0),h1=f2bf(v1),h2=f2bf(v2),h3=f2bf(v3);
      *(unsigned int*)&Ah[ar][aq]   = h0 | ((unsigned int)h1 << 16);
      *(unsigned int*)&Ah[ar][aq+2] = h2 | ((unsigned int)h3 << 16);
      unsigned short l0=f2bf(v0-bf2f(h0)),l1=f2bf(v1-bf2f(h1)),l2=f2bf(v2-bf2f(h2)),l3=f2bf(v3-bf2f(h3));
      *(unsigned int*)&Al[ar][aq]   = l0 | ((unsigned int)l1 << 16);
      *(unsigned int*)&Al[ar][aq+2] = l2 | ((unsigned int)l3 << 16);
    }
    #pragma unroll
    for (int ii = 0; ii < 4; ++ii) {
      const int idx = t + ii * 256, n = idx & 63, kk = (idx >> 6) * 2;
      const int gn = col0 + n;
      float v0 = (gn < N && kt + kk     < kend) ? B[(size_t)(kt + kk) * N + gn] : 0.f;
      float v1 = (gn < N && kt + kk + 1 < kend) ? B[(size_t)(kt + kk + 1) * N + gn] : 0.f;
      unsigned short h0 = f2bf(v0), h1 = f2bf(v1);
      *(unsigned int*)&Bh[n][kk] = h0 | ((unsigned int)h1 << 16);
      unsigned short l0 = f2bf(v0 - bf2f(h0)), l1 = f2bf(v1 - bf2f(h1));
      *(unsigned int*)&Bl[n][kk] = l0 | ((unsigned int)l1 << 16);
    }
    __syncthreads();
    const bf16x8 ah  = *(const bf16x8*)&Ah[w * 16 + r][g * 8];
    const bf16x8 al2 = *(const bf16x8*)&Al[w * 16 + r][g * 8];
    #pragma unroll
    for (int nt = 0; nt < 4; ++nt) {
      const bf16x8 bh = *(const bf16x8*)&Bh[nt * 16 + r][g * 8];
      const bf16x8 bl = *(const bf16x8*)&Bl[nt * 16 + r][g * 8];
      acc[nt] = __builtin_amdgcn_mfma_f32_16x16x32_bf16(ah,  bh, acc[nt], 0,0,0);
      acc[nt] = __builtin_amdgcn_mfma_f32_16x16x32_bf16(al2, bh, acc[nt], 0,0,0);
      acc[nt] = __builtin_amdgcn_mfma_f32_16x16x32_bf16(ah,  bl, acc[nt], 0,0,0);
    }
    __syncthreads();
  }
  float* Pout = P + (size_t)sk * M * N;
  #pragma unroll
  for (int nt = 0; nt < 4; ++nt) {
    const int cc = col0 + nt * 16 + r;
    if (cc < N) {
      #pragma unroll
      for (int q = 0; q < 4; ++q)
        Pout[(size_t)(row0 + w * 16 + g * 4 + q) * N + cc] = acc[nt][q];
    }
  }
}

// =============== batched pair variant: z<nskA -> problem A, else problem B ===============
__global__ __launch_bounds__(256) void k_gemm_sk2(
    const float* __restrict__ A1, const float* __restrict__ B1, float* __restrict__ P1o,
    const float* __restrict__ A2, const float* __restrict__ B2, float* __restrict__ P2o,
    int nskA, int M, int K, int N, int kpt)
{
  __shared__ unsigned short Ah[64][40], Al[64][40], Bh[64][40], Bl[64][40];
  const int t = threadIdx.x, lane = t & 63, w = t >> 6, r = lane & 15, g = lane >> 4;
  const int row0 = blockIdx.x * 64, col0 = blockIdx.y * 64;
  const int zz = blockIdx.z;
  const int second = (zz >= nskA);
  const int sk = second ? zz - nskA : zz;
  const float* A = second ? A2 : A1;
  const float* B = second ? B2 : B1;
  float* P = second ? P2o : P1o;
  const int k0 = sk * kpt * 32;
  const int kend = min(K, k0 + kpt * 32);

  f32x4 acc[4];
  #pragma unroll
  for (int nt = 0; nt < 4; ++nt) acc[nt] = (f32x4){0.f,0.f,0.f,0.f};

  for (int kt = k0; kt < kend; kt += 32) {
    #pragma unroll
    for (int ii = 0; ii < 2; ++ii) {
      const int idx = t + ii * 256, ar = idx >> 3, aq = (idx & 7) * 4, gk = kt + aq;
      const float* ap = &A[(size_t)(row0 + ar) * K + gk];
      float v0 = gk     < kend ? ap[0] : 0.f;
      float v1 = gk + 1 < kend ? ap[1] : 0.f;
      float v2 = gk + 2 < kend ? ap[2] : 0.f;
      float v3 = gk + 3 < kend ? ap[3] : 0.f;
      unsigned short h0=f2bf(v0),h1=f2bf(v1),h2=f2bf(v2),h3=f2bf(v3);
      *(unsigned int*)&Ah[ar][aq]   = h0 | ((unsigned int)h1 << 16);
      *(unsigned int*)&Ah[ar][aq+2] = h2 | ((unsigned int)h3 << 16);
      unsigned short l0=f2bf(v0-bf2f(h0)),l1=f2bf(v1-bf2f(h1)),l2=f2bf(v2-bf2f(h2)),l3=f2bf(v3-bf2f(h3));
      *(unsigned int*)&Al[ar][aq]   = l0 | ((unsigned int)l1 << 16);
      *(unsigned int*)&Al[ar][aq+2] = l2 | ((unsigned int)l3 << 16);
    }
    #pragma unroll
    for (int ii = 0; ii < 4; ++ii) {
      const int idx = t + ii * 256, n = idx & 63, kk = (idx >> 6) * 2;
      const int gn = col0 + n;
      float v0 = (gn < N && kt + kk     < kend) ? B[(size_t)(kt + kk) * N + gn] : 0.f;
      float v1 = (gn < N && kt + kk + 1 < kend) ? B[(size_t)(kt + kk + 1) * N + gn] : 0.f;
      unsigned short h0 = f2bf(v0), h1 = f2bf(v1);
      *(unsigned int*)&Bh[n][kk] = h0 | ((unsigned int)h1 << 16);
      unsigned short l0 = f2bf(v0 - bf2f(h0)), l1 = f2bf(v1 - bf2f(h1));
      *(unsigned int*)&Bl[n][kk] = l0 | ((unsigned int)l1 << 16);
    }
    __syncthreads();
    const bf16x8 ah  = *(const bf16x8*)&Ah[w * 16 + r][g * 8];
    const bf16x8 al2 = *(const bf16x8*)&Al[w * 16 + r][g * 8];
    #pragma unroll
    for (int nt = 0; nt < 4; ++nt) {
      const bf16x8 bh = *(const bf16x8*)&Bh[nt * 16 + r][g * 8];
      const bf16x8 bl = *(const bf16x8*)&Bl[nt * 16 + r][g * 8];
      acc[nt] = __builtin_amdgcn_mfma_f32_16x16x32_bf16(ah,  bh, acc[nt], 0,0,0);
      acc[nt] = __builtin_amdgcn_mfma_f32_16x16x32_bf16(al2, bh, acc[nt], 0,0,0);
      acc[nt] = __builtin_amdgcn_mfma_f32_16x16x32_bf16(ah,  bl, acc[nt], 0,0,0);
    }
    __syncthreads();
  }
  float* Pout = P + (size_t)sk * M * N;
  #pragma unroll
  for (int nt = 0; nt < 4; ++nt) {
    const int cc = col0 + nt * 16 + r;
    if (cc < N) {
      #pragma unroll
      for (int q = 0; q < 4; ++q)
        Pout[(size_t)(row0 + w * 16 + g * 4 + q) * N + cc] = acc[nt][q];
    }
  }
}

// =============== split-K reduce + bias + activation ===============
__global__ __launch_bounds__(256) void k_reduce(
    const float* __restrict__ P, const float* __restrict__ bias,
    float* __restrict__ C, int M, int N, int ldc, int nsk, int act)
{
  const int idx = blockIdx.x * 256 + threadIdx.x;
  if (idx >= M * N) return;
  const int row = idx / N, col = idx - row * N;
  float s = bias[col];
  for (int k = 0; k < nsk; ++k) s += P[(size_t)k * M * N + idx];
  if (act) s = fmaxf(s, 0.f);
  C[(size_t)row * ldc + col] = s;
}

// =============== batched pair reduce: first nblkA blocks -> A, rest -> B ===============
__global__ __launch_bounds__(256) void k_reduce2(
    const float* __restrict__ PA, const float* __restrict__ biasA, float* __restrict__ CA,
    const float* __restrict__ PB, const float* __restrict__ biasB, float* __restrict__ CB,
    int M, int N, int ldc, int nsk, int act, int nblkA)
{
  const int second = (blockIdx.x >= nblkA);
  const float* P = second ? PB : PA;
  const float* bias = second ? biasB : biasA;
  float* C = second ? CB : CA;
  const int idx = (second ? blockIdx.x - nblkA : blockIdx.x) * 256 + threadIdx.x;
  if (idx >= M * N) return;
  const int row = idx / N, col = idx - row * N;
  float s = bias[col];
  for (int k = 0; k < nsk; ++k) s += P[(size_t)k * M * N + idx];
  if (act) s = fmaxf(s, 0.f);
  C[(size_t)row * ldc + col] = s;
}

// =============== final GEMV + sigmoid ===============
__global__ __launch_bounds__(512) void k_out(
    const float* __restrict__ z1, const float* __restrict__ w2,
    const float* __restrict__ b2, float* __restrict__ out)
{
  const int t = threadIdx.x, lane = t & 63, w = t >> 6;
  const int b = blockIdx.x * 8 + w;
  float p = 0.f;
  for (int k = lane; k < 300; k += 64) p += z1[(size_t)b * 300 + k] * w2[k];
  p = warp_sum(p);
  if (lane == 0) out[b] = 1.f / (1.f + __expf(-(p + b2[0])));
}

extern "C" void kernel_launch(void* const* d_in, const int* in_sizes, int n_in,
                              void* d_out, int out_size, void* d_ws, size_t ws_size,
                              hipStream_t stream)
{
  const float* x    = (const float*)d_in[0];
  const int*   adj  = (const int*)d_in[1];
  const float* fp   = (const float*)d_in[2];
  const float* Whw  = (const float*)d_in[3];
  const float* asrc = (const float*)d_in[4];
  const float* adst = (const float*)d_in[5];
  const float* Wout = (const float*)d_in[6];
  const float* aos  = (const float*)d_in[7];
  const float* aod  = (const float*)d_in[8];
  const float* fc1w = (const float*)d_in[9];
  const float* fc1b = (const float*)d_in[10];
  const float* fc2w = (const float*)d_in[11];
  const float* fc2b = (const float*)d_in[12];
  const float* fcgw = (const float*)d_in[13];
  const float* fcgb = (const float*)d_in[14];
  const float* fcfw = (const float*)d_in[15];
  const float* fcfb = (const float*)d_in[16];
  const float* f1w  = (const float*)d_in[17];
  const float* f1b  = (const float*)d_in[18];
  const float* f2w  = (const float*)d_in[19];
  const float* f2b  = (const float*)d_in[20];
  float* out = (float*)d_out;

  char* wsb = (char*)d_ws;
  unsigned int* buf1 = (unsigned int*)wsb;
  float* s1g = (float*)(wsb + 125829120);
  float* d1g = (float*)(wsb + 127926272);
  float* s2g = (float*)(wsb + 130023424);
  float* d2g = (float*)(wsb + 130285568);
  u64*   mgb = (u64*)  (wsb + 130547712);
  float* gatp = (float*)(wsb + 131596288);
  float* fpnp = (float*)(wsb + 132210688);
  float* f1buf = (float*)(wsb + 132825088);
  float* zb    = (float*)(wsb + 133873664);
  float* z1b   = (float*)(wsb + 135102464);
  float* P0 = (float*)(wsb + 135716864);
  float* P1 = (float*)(wsb + 142008320);
  float* P2 = (float*)(wsb + 144465920);
  float* P3 = (float*)(wsb + 145694720);
  float* P4 = (float*)(wsb + 146923520);
  unsigned short* Bf1H = (unsigned short*)(wsb + 149381120);
  unsigned short* Bf1L = (unsigned short*)(wsb + 149544960);
  unsigned short* Bf2H = (unsigned short*)(wsb + 149708800);
  unsigned short* Bf2L = (unsigned short*)(wsb + 150016000);

  // setup: mask + both weight preps in one launch
  k_setup<<<627, 256, 0, stream>>>(adj, mgb, Whw, Bf1H, Bf1L, Wout, Bf2H, Bf2L);
  // --- GAT chain (unchanged 341 µs baseline) ---
  k_gemm1<<<2048, 512, 0, stream>>>(x, Bf1H, Bf1L, asrc, adst, buf1, s1g, d1g);
  k_att1 <<<4096, 256, 0, stream>>>(buf1, mgb, s1g, d1g);
  k_gemm2<<<1024, 256, 0, stream>>>(buf1, Bf2H, Bf2L, aos, aod, s2g, d2g);
  // att2 batched with independent fc1 GEMM (512 att2 blocks + 384 fc1 blocks)
  k_att2fc1<<<896, 256, 0, stream>>>(buf1, mgb, s2g, d2g, gatp, fp, fc1w, P0);
  // --- head chain ---
  k_reduce<<<1024, 256, 0, stream>>>(P0, fc1b, f1buf, 512, 512, 512, 6, 1);
  k_gemm_sk<<<dim3(8,5,4), 256, 0, stream>>>(f1buf, fc2w, P1, 512, 512, 300, 4);
  k_reduce<<<600, 256, 0, stream>>>(P1, fc2b, fpnp, 512, 300, 300, 4, 0);
  k_gemm_sk2<<<dim3(8,5,4), 256, 0, stream>>>(gatp, fcgw, P2, fpnp, fcfw, P3,
                                              2, 512, 300, 300, 5);
  k_reduce2<<<1200, 256, 0, stream>>>(P2, fcgb, zb, P3, fcfb, zb + 300,
                                      512, 300, 600, 2, 1, 600);
  k_gemm_sk<<<dim3(8,5,4), 256, 0, stream>>>(zb, f1w, P4, 512, 600, 300, 5);
  k_reduce<<<600, 256, 0, stream>>>(P4, f1b, z1b, 512, 300, 300, 4, 1);
  k_out<<<64, 512, 0, stream>>>(z1b, f2w, f2b, out);
}

// Round 19
// 330.058 us; speedup vs baseline: 1.2216x; 1.0009x over previous
//
#include <hip/hip_runtime.h>
#include <hip/hip_bf16.h>
#include <math.h>
#include <stdint.h>

#define LRA 0.2f

typedef __attribute__((ext_vector_type(8))) short bf16x8;
typedef __attribute__((ext_vector_type(8))) unsigned short u16x8;
typedef __attribute__((ext_vector_type(4))) float f32x4;
typedef unsigned long long u64;

__device__ __forceinline__ unsigned short f2bf(float v) {
  union { __hip_bfloat16 b; unsigned short u; } c;
  c.b = __float2bfloat16(v);
  return c.u;
}
__device__ __forceinline__ float bf2f(unsigned short h) {
  union { float f; unsigned int u; } a; a.u = ((unsigned int)h) << 16;
  return a.f;
}
__device__ __forceinline__ float warp_sum(float v){
  #pragma unroll
  for (int s = 32; s; s >>= 1) v += __shfl_xor(v, s);
  return v;
}

// =============== setup: adjacency masks + both weight preps in ONE launch ===============
__global__ __launch_bounds__(256) void k_setup(
    const int* __restrict__ adj, u64* __restrict__ mg,
    const float* __restrict__ Whw, unsigned short* __restrict__ B1H, unsigned short* __restrict__ B1L,
    const float* __restrict__ W, unsigned short* __restrict__ B2H, unsigned short* __restrict__ B2L)
{
  const int bid = blockIdx.x, t = threadIdx.x;
  if (bid < 512) {
    const int lane = t & 63, w = t >> 6, b = bid;
    const int* adjb = adj + (size_t)b * 128 * 128;
    for (int i = w * 32; i < w * 32 + 32; ++i) {
      u64 b0 = __ballot(adjb[i * 128 + lane] > 0);
      u64 b1 = __ballot(adjb[i * 128 + 64 + lane] > 0);
      if (lane == 0) { mg[((size_t)b * 128 + i) * 2] = b0; mg[((size_t)b * 128 + i) * 2 + 1] = b1; }
    }
  } else if (bid < 552) {
    const int unit = (bid - 512) * 4 + (t >> 6);
    const int kt = unit >> 5, nt = unit & 31, l = t & 63;
    const int n = nt * 16 + (l & 15), k0 = kt * 32 + (l >> 4) * 8;
    const int hd = n / 60, j = n - hd * 60;
    uint4 hv, lv;
    unsigned int* hp = (unsigned int*)&hv;
    unsigned int* lp = (unsigned int*)&lv;
    #pragma unroll
    for (int p = 0; p < 4; ++p) {
      unsigned short hh[2], ll[2];
      #pragma unroll
      for (int e = 0; e < 2; ++e) {
        const int k = k0 + p * 2 + e;
        const float v = (n < 480 && k < 133) ? Whw[((size_t)hd * 133 + k) * 60 + j] : 0.f;
        const unsigned short h = f2bf(v);
        hh[e] = h; ll[e] = f2bf(v - bf2f(h));
      }
      hp[p] = hh[0] | ((unsigned int)hh[1] << 16);
      lp[p] = ll[0] | ((unsigned int)ll[1] << 16);
    }
    const size_t off = (((size_t)(kt * 32 + nt)) * 64 + l) * 8;
    *(uint4*)&B1H[off] = hv;
    *(uint4*)&B1L[off] = lv;
  } else {
    const int unit = (bid - 552) * 4 + (t >> 6);
    const int kt = unit / 20, nt = unit - kt * 20, l = t & 63;
    const int n = nt * 16 + (l & 15), k0 = kt * 32 + (l >> 4) * 8;
    uint4 hv, lv;
    unsigned int* hp = (unsigned int*)&hv;
    unsigned int* lp = (unsigned int*)&lv;
    #pragma unroll
    for (int p = 0; p < 4; ++p) {
      unsigned short hh[2], ll[2];
      #pragma unroll
      for (int e = 0; e < 2; ++e) {
        const int k = k0 + p * 2 + e;
        const float v = (n < 300 && k < 480) ? W[(size_t)k * 300 + n] : 0.f;
        const unsigned short h = f2bf(v);
        hh[e] = h; ll[e] = f2bf(v - bf2f(h));
      }
      hp[p] = hh[0] | ((unsigned int)hh[1] << 16);
      lp[p] = ll[0] | ((unsigned int)ll[1] << 16);
    }
    const size_t off = (((size_t)(kt * 20 + nt)) * 64 + l) * 8;
    *(uint4*)&B2H[off] = hv;
    *(uint4*)&B2L[off] = lv;
  }
}

// =============== GEMM1: Wh = x @ Bcat; 4 row-parts per batch ===============
__global__ __launch_bounds__(512) void k_gemm1(
    const float* __restrict__ x,
    const unsigned short* __restrict__ BH, const unsigned short* __restrict__ BL,
    const float* __restrict__ asrc, const float* __restrict__ adst,
    unsigned int* __restrict__ buf1, float* __restrict__ s1g, float* __restrict__ d1g)
{
  __shared__ unsigned int Apk[32][32];
  __shared__ float asl[512], adl[512];
  __shared__ float sp0[8][32], sp1[8][32], dp0[8][32], dp1[8][32];
  const int t = threadIdx.x, lane = t & 63, w = t >> 6, r = lane & 15, g = lane >> 4;
  const int b = blockIdx.x >> 2, p = blockIdx.x & 3;
  const int row0 = p * 32;
  const float* xb = x + (size_t)b * 128 * 133;
  unsigned int* slab = buf1 + (size_t)b * 61440;

  asl[t] = (t < 480) ? asrc[t] : 0.f;
  adl[t] = (t < 480) ? adst[t] : 0.f;

  f32x4 acc[2][4];
  #pragma unroll
  for (int mt = 0; mt < 2; ++mt)
    #pragma unroll
    for (int ntl = 0; ntl < 4; ++ntl) acc[mt][ntl] = (f32x4){0.f,0.f,0.f,0.f};

  for (int kt = 0; kt < 5; ++kt) {
    if (t < 256) {
      const int row_l = t >> 3, sl = t & 7;
      const int k0 = kt * 32 + sl * 4;
      uint4 pk;
      unsigned int* pp = (unsigned int*)&pk;
      #pragma unroll
      for (int e = 0; e < 4; ++e) {
        const int k = k0 + e;
        const float v = (k < 133) ? xb[(size_t)(row0 + row_l) * 133 + k] : 0.f;
        const unsigned short h = f2bf(v);
        pp[e] = ((unsigned int)h << 16) | f2bf(v - bf2f(h));
      }
      *(uint4*)&Apk[row_l][((sl ^ (row_l & 7)) << 2)] = pk;
    }
    bf16x8 bh[4], bl[4];
    #pragma unroll
    for (int ntl = 0; ntl < 4; ++ntl) {
      const int nt = w * 4 + ntl;
      const size_t off = (((size_t)(kt * 32 + nt)) * 64 + lane) * 8;
      bh[ntl] = *(const bf16x8*)&BH[off];
      bl[ntl] = *(const bf16x8*)&BL[off];
    }
    __syncthreads();
    #pragma unroll
    for (int mt = 0; mt < 2; ++mt) {
      const int row_l = mt * 16 + r, key = r & 7;
      const uint4 p0 = *(const uint4*)&Apk[row_l][(((2*g)   ^ key) << 2)];
      const uint4 p1 = *(const uint4*)&Apk[row_l][(((2*g+1) ^ key) << 2)];
      const unsigned int pw[8] = {p0.x,p0.y,p0.z,p0.w,p1.x,p1.y,p1.z,p1.w};
      bf16x8 ah, al;
      #pragma unroll
      for (int e = 0; e < 8; ++e) { ah[e] = (short)(pw[e] >> 16); al[e] = (short)(pw[e] & 0xffffu); }
      #pragma unroll
      for (int ntl = 0; ntl < 4; ++ntl) {
        acc[mt][ntl] = __builtin_amdgcn_mfma_f32_16x16x32_bf16(ah, bh[ntl], acc[mt][ntl], 0,0,0);
        acc[mt][ntl] = __builtin_amdgcn_mfma_f32_16x16x32_bf16(al, bh[ntl], acc[mt][ntl], 0,0,0);
        acc[mt][ntl] = __builtin_amdgcn_mfma_f32_16x16x32_bf16(ah, bl[ntl], acc[mt][ntl], 0,0,0);
      }
    }
    __syncthreads();
  }
  #pragma unroll
  for (int mt = 0; mt < 2; ++mt)
    #pragma unroll
    for (int ntl = 0; ntl < 4; ++ntl) {
      const int cc = (w * 4 + ntl) * 16 + r;
      if (cc < 480) {
        const int hd = cc / 60, cl = cc - hd * 60;
        uint4 pv;
        unsigned int* pp = (unsigned int*)&pv;
        #pragma unroll
        for (int q = 0; q < 4; ++q) {
          const float v = acc[mt][ntl][q];
          const unsigned short h = f2bf(v);
          pp[q] = ((unsigned int)h << 16) | f2bf(v - bf2f(h));
        }
        *(uint4*)&slab[(size_t)hd * 7680 + (size_t)cl * 128 + row0 + mt * 16 + (g << 2)] = pv;
      }
    }
  const int thr0 = 60 - 4 * w;
  #pragma unroll
  for (int mt = 0; mt < 2; ++mt) {
    #pragma unroll
    for (int q = 0; q < 4; ++q) {
      float s0 = 0.f, s1 = 0.f, d0 = 0.f, d1 = 0.f;
      #pragma unroll
      for (int ntl = 0; ntl < 4; ++ntl) {
        const int loc = ntl * 16 + r;
        const int cc = w * 64 + loc;
        const float a = acc[mt][ntl][q];
        const float as = asl[cc], ad = adl[cc];
        if (loc < thr0) { s0 += a * as; d0 += a * ad; }
        else            { s1 += a * as; d1 += a * ad; }
      }
      #pragma unroll
      for (int s = 1; s <= 8; s <<= 1) {
        s0 += __shfl_xor(s0, s); s1 += __shfl_xor(s1, s);
        d0 += __shfl_xor(d0, s); d1 += __shfl_xor(d1, s);
      }
      if (r == 0) {
        const int row_l = mt * 16 + g * 4 + q;
        sp0[w][row_l] = s0; sp1[w][row_l] = s1;
        dp0[w][row_l] = d0; dp1[w][row_l] = d1;
      }
    }
  }
  __syncthreads();
  if (t < 256) {
    const int hd = t >> 5, row_l = t & 31;
    s1g[((size_t)b * 8 + hd) * 128 + row0 + row_l] = sp0[hd][row_l] + (hd > 0 ? sp1[hd-1][row_l] : 0.f);
    d1g[((size_t)b * 8 + hd) * 128 + row0 + row_l] = dp0[hd][row_l] + (hd > 0 ? dp1[hd-1][row_l] : 0.f);
  }
}

// ===== merged attention-fragment generator (shared by att1/att2) =====
__device__ __forceinline__ float make_att_frags(
    const float si, const u64 ma, const u64 mb2, const float* darr,
    const int g, bf16x8* pah, bf16x8* pal)
{
  const unsigned int mby[4] = {
    (unsigned int)(ma  >> (g * 8)) & 0xffu,
    (unsigned int)(ma  >> (32 + g * 8)) & 0xffu,
    (unsigned int)(mb2 >> (g * 8)) & 0xffu,
    (unsigned int)(mb2 >> (32 + g * 8)) & 0xffu };
  float ev[4][8];
  float mx = -3e38f;
  #pragma unroll
  for (int kt = 0; kt < 4; ++kt)
    #pragma unroll
    for (int e = 0; e < 8; ++e) {
      const int j = ((kt & 1) * 32) + ((kt >> 1) * 64) + g * 8 + e;
      float v = si + darr[j];
      v = fmaxf(v, LRA * v);
      const float vv = (mby[((kt & 1) << 1) | (kt >> 1)] & (1u << e)) ? v : -3e38f;
      ev[kt][e] = vv;
      mx = fmaxf(mx, vv);
    }
  mx = fmaxf(mx, __shfl_xor(mx, 16));
  mx = fmaxf(mx, __shfl_xor(mx, 32));
  float sum = 0.f;
  #pragma unroll
  for (int kt = 0; kt < 4; ++kt)
    #pragma unroll
    for (int e = 0; e < 8; ++e) {
      const float p = (ev[kt][e] > -1e37f) ? __expf(ev[kt][e] - mx) : 0.f;
      ev[kt][e] = p;
      sum += p;
    }
  sum += __shfl_xor(sum, 16);
  sum += __shfl_xor(sum, 32);
  #pragma unroll
  for (int kt = 0; kt < 4; ++kt) {
    const int ks = ((kt & 1) << 1) | (kt >> 1);
    union { unsigned int u[4]; bf16x8 v; } hw, lw;
    #pragma unroll
    for (int p2 = 0; p2 < 4; ++p2) {
      const float p0 = ev[ks][2 * p2], p1 = ev[ks][2 * p2 + 1];
      const unsigned short h0 = f2bf(p0), h1 = f2bf(p1);
      hw.u[p2] = h0 | ((unsigned int)h1 << 16);
      lw.u[p2] = f2bf(p0 - bf2f(h0)) | ((unsigned int)f2bf(p1 - bf2f(h1)) << 16);
    }
    pah[kt] = hw.v;
    pal[kt] = lw.v;
  }
  return 1.f / sum;
}

// =============== att1: per (b,head); h = elu(att@Wh) in-place ===============
__global__ __launch_bounds__(256) void k_att1(
    unsigned int* __restrict__ buf1, const u64* __restrict__ mg,
    const float* __restrict__ s1g, const float* __restrict__ d1g)
{
  __shared__ unsigned short Th[16][64][8], Tl[16][64][8];
  __shared__ float sarr[128], darr[128];
  __shared__ u64 mAr[128], mBr[128];
  const int t = threadIdx.x, lane = t & 63, w = t >> 6, r = lane & 15, g = lane >> 4;
  const int bid = blockIdx.x;
  const int lb = ((bid & 7) << 9) | (bid >> 3);
  const int b = lb >> 3, hd = lb & 7;
  const size_t sl = (size_t)b * 8 + hd;
  unsigned int* slab = buf1 + sl * 7680;

  if (t < 128) {
    sarr[t] = s1g[sl * 128 + t];
    darr[t] = d1g[sl * 128 + t];
    mAr[t] = mg[((size_t)b * 128 + t) * 2];
    mBr[t] = mg[((size_t)b * 128 + t) * 2 + 1];
  }
  #pragma unroll
  for (int ii = 0; ii < 4; ++ii) {
    const int idx = t + ii * 256;
    const int c = idx & 63, jg = idx >> 6;
    uint4 p0 = {0,0,0,0}, p1 = {0,0,0,0};
    if (c < 60) {
      const uint4* src = (const uint4*)&slab[(size_t)c * 128 + jg * 8];
      p0 = src[0]; p1 = src[1];
    }
    const unsigned int pw[8] = {p0.x,p0.y,p0.z,p0.w,p1.x,p1.y,p1.z,p1.w};
    u16x8 hv, lv;
    #pragma unroll
    for (int e = 0; e < 8; ++e) { hv[e] = (unsigned short)(pw[e] >> 16); lv[e] = (unsigned short)(pw[e] & 0xffffu); }
    const int tile = ((c >> 4) << 2) | (jg >> 2);
    const int li = ((jg & 3) << 4) | (c & 15);
    *(u16x8*)&Th[tile][li][0] = hv;
    *(u16x8*)&Tl[tile][li][0] = lv;
  }
  __syncthreads();
  bf16x8 pah[2][4], pal[2][4];
  float inv2[2];
  #pragma unroll
  for (int mt = 0; mt < 2; ++mt) {
    const int i = w * 32 + mt * 16 + r;
    inv2[mt] = make_att_frags(sarr[i], mAr[i], mBr[i], darr, g, pah[mt], pal[mt]);
  }
  f32x4 acc[2][4];
  #pragma unroll
  for (int mt = 0; mt < 2; ++mt)
    #pragma unroll
    for (int nt = 0; nt < 4; ++nt) acc[mt][nt] = (f32x4){0.f,0.f,0.f,0.f};
  #pragma unroll
  for (int kt = 0; kt < 4; ++kt)
    #pragma unroll
    for (int nt = 0; nt < 4; ++nt) {
      const bf16x8 bh = *(const bf16x8*)&Th[(nt << 2) | kt][lane][0];
      const bf16x8 bl = *(const bf16x8*)&Tl[(nt << 2) | kt][lane][0];
      #pragma unroll
      for (int mt = 0; mt < 2; ++mt) {
        acc[mt][nt] = __builtin_amdgcn_mfma_f32_16x16x32_bf16(pah[mt][kt], bh, acc[mt][nt], 0,0,0);
        acc[mt][nt] = __builtin_amdgcn_mfma_f32_16x16x32_bf16(pal[mt][kt], bh, acc[mt][nt], 0,0,0);
        acc[mt][nt] = __builtin_amdgcn_mfma_f32_16x16x32_bf16(pah[mt][kt], bl, acc[mt][nt], 0,0,0);
      }
    }
  #pragma unroll
  for (int mt = 0; mt < 2; ++mt) {
    float sc[4];
    #pragma unroll
    for (int q = 0; q < 4; ++q) sc[q] = __shfl(inv2[mt], g * 4 + q);
    #pragma unroll
    for (int nt = 0; nt < 4; ++nt) {
      const int cc = nt * 16 + r;
      if (cc < 60) {
        #pragma unroll
        for (int q = 0; q < 4; ++q) {
          const int row = w * 32 + mt * 16 + g * 4 + q;
          float v = acc[mt][nt][q] * sc[q];
          v = v > 0.f ? v : __expf(v) - 1.f;
          const unsigned short h = f2bf(v), l = f2bf(v - bf2f(h));
          slab[(size_t)row * 60 + cc] = ((unsigned int)h << 16) | l;
        }
      }
    }
  }
}

// =============== GEMM2: Wo = h @ W_out; 2 row-parts (64 rows) per batch ===============
__global__ __launch_bounds__(256, 3) void k_gemm2(
    unsigned int* __restrict__ buf1,
    const unsigned short* __restrict__ BH, const unsigned short* __restrict__ BL,
    const float* __restrict__ aos, const float* __restrict__ aod,
    float* __restrict__ s2g, float* __restrict__ d2g)
{
  __shared__ unsigned int Apk[64][32];
  __shared__ float aosl[320], aodl[320];
  __shared__ float sred[4][64], dred[4][64];
  const int t = threadIdx.x, lane = t & 63, w = t >> 6, r = lane & 15, g = lane >> 4;
  const int b = blockIdx.x >> 1, p = blockIdx.x & 1;
  const int row0 = p * 64;
  unsigned int* slab = buf1 + (size_t)b * 61440;
  if (t < 320) { aosl[t] = t < 300 ? aos[t] : 0.f; aodl[t] = t < 300 ? aod[t] : 0.f; }

  f32x4 acc[4][5];
  #pragma unroll
  for (int mt = 0; mt < 4; ++mt)
    #pragma unroll
    for (int ntl = 0; ntl < 5; ++ntl) acc[mt][ntl] = (f32x4){0.f,0.f,0.f,0.f};

  for (int kt = 0; kt < 15; ++kt) {
    #pragma unroll
    for (int i = 0; i < 2; ++i) {
      const int idx = t + i * 256, row_l = idx >> 3, sl = idx & 7;
      const int k0 = kt * 32 + sl * 4;
      const int hd = k0 / 60, c = k0 - hd * 60;
      const uint4 v = *(const uint4*)&slab[(size_t)hd * 7680 + (size_t)(row0 + row_l) * 60 + c];
      *(uint4*)&Apk[row_l][((sl ^ (row_l & 7)) << 2)] = v;
    }
    bf16x8 bh[5], bl[5];
    #pragma unroll
    for (int ntl = 0; ntl < 5; ++ntl) {
      const int nt = w * 5 + ntl;
      const size_t off = (((size_t)(kt * 20 + nt)) * 64 + lane) * 8;
      bh[ntl] = *(const bf16x8*)&BH[off];
      bl[ntl] = *(const bf16x8*)&BL[off];
    }
    __syncthreads();
    #pragma unroll
    for (int mt = 0; mt < 4; ++mt) {
      const int row_l = mt * 16 + r, key = r & 7;
      const uint4 p0 = *(const uint4*)&Apk[row_l][(((2*g)   ^ key) << 2)];
      const uint4 p1 = *(const uint4*)&Apk[row_l][(((2*g+1) ^ key) << 2)];
      const unsigned int pw[8] = {p0.x,p0.y,p0.z,p0.w,p1.x,p1.y,p1.z,p1.w};
      bf16x8 ah, al;
      #pragma unroll
      for (int e = 0; e < 8; ++e) { ah[e] = (short)(pw[e] >> 16); al[e] = (short)(pw[e] & 0xffffu); }
      #pragma unroll
      for (int ntl = 0; ntl < 5; ++ntl) {
        acc[mt][ntl] = __builtin_amdgcn_mfma_f32_16x16x32_bf16(ah, bh[ntl], acc[mt][ntl], 0,0,0);
        acc[mt][ntl] = __builtin_amdgcn_mfma_f32_16x16x32_bf16(al, bh[ntl], acc[mt][ntl], 0,0,0);
        acc[mt][ntl] = __builtin_amdgcn_mfma_f32_16x16x32_bf16(ah, bl[ntl], acc[mt][ntl], 0,0,0);
      }
    }
    __syncthreads();
  }
  #pragma unroll
  for (int mt = 0; mt < 4; ++mt)
    #pragma unroll
    for (int ntl = 0; ntl < 5; ++ntl) {
      const int cc = w * 80 + ntl * 16 + r;
      if (cc < 300) {
        uint4 pv;
        unsigned int* pp = (unsigned int*)&pv;
        #pragma unroll
        for (int q = 0; q < 4; ++q) {
          const float v = acc[mt][ntl][q];
          const unsigned short h = f2bf(v);
          pp[q] = ((unsigned int)h << 16) | f2bf(v - bf2f(h));
        }
        *(uint4*)&slab[(size_t)cc * 128 + row0 + mt * 16 + (g << 2)] = pv;
      }
    }
  #pragma unroll
  for (int mt = 0; mt < 4; ++mt) {
    #pragma unroll
    for (int q = 0; q < 4; ++q) {
      float sv = 0.f, dv = 0.f;
      #pragma unroll
      for (int ntl = 0; ntl < 5; ++ntl) {
        const int cc = w * 80 + ntl * 16 + r;
        const float a = acc[mt][ntl][q];
        sv += a * aosl[cc]; dv += a * aodl[cc];
      }
      #pragma unroll
      for (int s = 1; s <= 8; s <<= 1) { sv += __shfl_xor(sv, s); dv += __shfl_xor(dv, s); }
      if (r == 0) {
        const int row_l = mt * 16 + g * 4 + q;
        sred[w][row_l] = sv; dred[w][row_l] = dv;
      }
    }
  }
  __syncthreads();
  if (t < 64) {
    s2g[(size_t)b * 128 + row0 + t] = sred[0][t] + sred[1][t] + sred[2][t] + sred[3][t];
    d2g[(size_t)b * 128 + row0 + t] = dred[0][t] + dred[1][t] + dred[2][t] + dred[3][t];
  }
}

// =============== BATCHED: att2 (bid<512) + fc1 split-K GEMM (bid>=512) ===============
__global__ __launch_bounds__(256) void k_att2fc1(
    const unsigned int* __restrict__ buf1, const u64* __restrict__ mg,
    const float* __restrict__ s2g, const float* __restrict__ d2g,
    float* __restrict__ gat,
    const float* __restrict__ fp, const float* __restrict__ fc1w, float* __restrict__ P0)
{
  __shared__ __align__(16) char SMEM[37120];
  const int t = threadIdx.x, lane = t & 63, w = t >> 6, r = lane & 15, g = lane >> 4;
  if (blockIdx.x < 512) {
    unsigned short* ThB = (unsigned short*)SMEM;
    unsigned short* TlB = ThB + 8192;
    float* sarr = (float*)(SMEM + 32768);
    float* darr = sarr + 128;
    u64* mAr = (u64*)(SMEM + 33792);
    u64* mBr = mAr + 128;
    float* colsum = (float*)(SMEM + 35840);
    float* srow = colsum + 304;
    const int b = blockIdx.x;
    const unsigned int* slab = buf1 + (size_t)b * 61440;

    if (t < 128) {
      sarr[t] = s2g[(size_t)b * 128 + t];
      darr[t] = d2g[(size_t)b * 128 + t];
      mAr[t] = mg[((size_t)b * 128 + t) * 2];
      mBr[t] = mg[((size_t)b * 128 + t) * 2 + 1];
    }
    for (int c = t; c < 304; c += 256) colsum[c] = 0.f;
    __syncthreads();
    bf16x8 pah[2][4], pal[2][4];
    float inv2[2];
    #pragma unroll
    for (int mt = 0; mt < 2; ++mt) {
      const int i = w * 32 + mt * 16 + r;
      inv2[mt] = make_att_frags(sarr[i], mAr[i], mBr[i], darr, g, pah[mt], pal[mt]);
    }
    float scq[2][4];
    #pragma unroll
    for (int mt = 0; mt < 2; ++mt)
      #pragma unroll
      for (int q = 0; q < 4; ++q) scq[mt][q] = __shfl(inv2[mt], g * 4 + q);

    float m8[2][4], l8[2][4];
    #pragma unroll
    for (int mt = 0; mt < 2; ++mt)
      #pragma unroll
      for (int q = 0; q < 4; ++q) { m8[mt][q] = -3e38f; l8[mt][q] = 0.f; }

    for (int ch = 0; ch < 5; ++ch) {
      #pragma unroll
      for (int ii = 0; ii < 4; ++ii) {
        const int idx = t + ii * 256;
        const int c = idx & 63, jg = idx >> 6;
        const int gc = ch * 64 + c;
        uint4 p0 = {0,0,0,0}, p1 = {0,0,0,0};
        if (gc < 300) {
          const uint4* src = (const uint4*)&slab[(size_t)gc * 128 + jg * 8];
          p0 = src[0]; p1 = src[1];
        }
        const unsigned int pw[8] = {p0.x,p0.y,p0.z,p0.w,p1.x,p1.y,p1.z,p1.w};
        u16x8 hv, lv;
        #pragma unroll
        for (int e = 0; e < 8; ++e) { hv[e] = (unsigned short)(pw[e] >> 16); lv[e] = (unsigned short)(pw[e] & 0xffffu); }
        const int tile = ((c >> 4) << 2) | (jg >> 2);
        const int li = ((jg & 3) << 4) | (c & 15);
        *(u16x8*)&ThB[((size_t)tile * 64 + li) * 8] = hv;
        *(u16x8*)&TlB[((size_t)tile * 64 + li) * 8] = lv;
      }
      __syncthreads();
      f32x4 pacc[2][4];
      #pragma unroll
      for (int mt = 0; mt < 2; ++mt)
        #pragma unroll
        for (int nt = 0; nt < 4; ++nt) pacc[mt][nt] = (f32x4){0.f,0.f,0.f,0.f};
      #pragma unroll
      for (int kt = 0; kt < 4; ++kt)
        #pragma unroll
        for (int nt = 0; nt < 4; ++nt) {
          const bf16x8 bh = *(const bf16x8*)&ThB[(((nt << 2) | kt) * 64 + lane) * 8];
          const bf16x8 bl = *(const bf16x8*)&TlB[(((nt << 2) | kt) * 64 + lane) * 8];
          #pragma unroll
          for (int mt = 0; mt < 2; ++mt) {
            pacc[mt][nt] = __builtin_amdgcn_mfma_f32_16x16x32_bf16(pah[mt][kt], bh, pacc[mt][nt], 0,0,0);
            pacc[mt][nt] = __builtin_amdgcn_mfma_f32_16x16x32_bf16(pal[mt][kt], bh, pacc[mt][nt], 0,0,0);
            pacc[mt][nt] = __builtin_amdgcn_mfma_f32_16x16x32_bf16(pah[mt][kt], bl, pacc[mt][nt], 0,0,0);
          }
        }
      float csA[4] = {0,0,0,0};
      #pragma unroll
      for (int mt = 0; mt < 2; ++mt) {
        float vq[4][4];
        #pragma unroll
        for (int nt = 0; nt < 4; ++nt) {
          const int cc = ch * 64 + nt * 16 + r;
          const bool cv = cc < 300;
          #pragma unroll
          for (int q = 0; q < 4; ++q) {
            float v = pacc[mt][nt][q] * scq[mt][q];
            v = v > 0.f ? v : __expf(v) - 1.f;
            vq[nt][q] = cv ? v : -3e38f;
            csA[nt] += cv ? v : 0.f;
          }
        }
        #pragma unroll
        for (int q = 0; q < 4; ++q) {
          float mx = fmaxf(fmaxf(vq[0][q], vq[1][q]), fmaxf(vq[2][q], vq[3][q]));
          mx = fmaxf(mx, __shfl_xor(mx, 1));
          mx = fmaxf(mx, __shfl_xor(mx, 2));
          mx = fmaxf(mx, __shfl_xor(mx, 4));
          mx = fmaxf(mx, __shfl_xor(mx, 8));
          const float nm = fmaxf(m8[mt][q], mx);
          float ps = __expf(vq[0][q]-nm) + __expf(vq[1][q]-nm) + __expf(vq[2][q]-nm) + __expf(vq[3][q]-nm);
          ps += __shfl_xor(ps, 1); ps += __shfl_xor(ps, 2);
          ps += __shfl_xor(ps, 4); ps += __shfl_xor(ps, 8);
          l8[mt][q] = l8[mt][q] * __expf(m8[mt][q] - nm) + ps;
          m8[mt][q] = nm;
        }
      }
      #pragma unroll
      for (int nt = 0; nt < 4; ++nt) {
        float cs = csA[nt];
        cs += __shfl_xor(cs, 16); cs += __shfl_xor(cs, 32);
        const int cc = ch * 64 + nt * 16 + r;
        if (g == 0 && cc < 300) atomicAdd(&colsum[cc], cs);
      }
      __syncthreads();
    }
    if (r == 0) {
      float sp = 0.f;
      #pragma unroll
      for (int mt = 0; mt < 2; ++mt)
        #pragma unroll
        for (int q = 0; q < 4; ++q) sp += m8[mt][q] + __logf(l8[mt][q]);
      srow[w * 4 + g] = sp;
    }
    __syncthreads();
    float S = 0.f;
    #pragma unroll
    for (int k = 0; k < 16; ++k) S += srow[k];
    for (int c = t; c < 300; c += 256)
      gat[(size_t)b * 300 + c] = (colsum[c] - S) * (1.f / 128.f);
  } else {
    unsigned short* Ah = (unsigned short*)SMEM;
    unsigned short* Al = Ah + 2560;
    unsigned short* Bh = Ah + 5120;
    unsigned short* Bl = Ah + 7680;
    const int idx0 = blockIdx.x - 512;
    const int row0 = (idx0 & 7) * 64, col0 = ((idx0 >> 3) & 7) * 64;
    const int sk = idx0 >> 6;
    const int M = 512, K = 1489, N = 512, kpt = 8;
    const float* A = fp;
    const float* B = fc1w;
    const int k0 = sk * kpt * 32;
    const int kend = min(K, k0 + kpt * 32);

    f32x4 acc[4];
    #pragma unroll
    for (int nt = 0; nt < 4; ++nt) acc[nt] = (f32x4){0.f,0.f,0.f,0.f};

    for (int kt = k0; kt < kend; kt += 32) {
      #pragma unroll
      for (int ii = 0; ii < 2; ++ii) {
        const int idx = t + ii * 256, ar = idx >> 3, aq = (idx & 7) * 4, gk = kt + aq;
        const float* ap = &A[(size_t)(row0 + ar) * K + gk];
        float v0 = gk     < kend ? ap[0] : 0.f;
        float v1 = gk + 1 < kend ? ap[1] : 0.f;
        float v2 = gk + 2 < kend ? ap[2] : 0.f;
        float v3 = gk + 3 < kend ? ap[3] : 0.f;
        unsigned short h0=f2bf(v0),h1=f2bf(v1),h2=f2bf(v2),h3=f2bf(v3);
        *(unsigned int*)&Ah[ar * 40 + aq]     = h0 | ((unsigned int)h1 << 16);
        *(unsigned int*)&Ah[ar * 40 + aq + 2] = h2 | ((unsigned int)h3 << 16);
        unsigned short l0=f2bf(v0-bf2f(h0)),l1=f2bf(v1-bf2f(h1)),l2=f2bf(v2-bf2f(h2)),l3=f2bf(v3-bf2f(h3));
        *(unsigned int*)&Al[ar * 40 + aq]     = l0 | ((unsigned int)l1 << 16);
        *(unsigned int*)&Al[ar * 40 + aq + 2] = l2 | ((unsigned int)l3 << 16);
      }
      #pragma unroll
      for (int ii = 0; ii < 4; ++ii) {
        const int idx = t + ii * 256, n = idx & 63, kk = (idx >> 6) * 2;
        const int gn = col0 + n;
        float v0 = (gn < N && kt + kk     < kend) ? B[(size_t)(kt + kk) * N + gn] : 0.f;
        float v1 = (gn < N && kt + kk + 1 < kend) ? B[(size_t)(kt + kk + 1) * N + gn] : 0.f;
        unsigned short h0 = f2bf(v0), h1 = f2bf(v1);
        *(unsigned int*)&Bh[n * 40 + kk] = h0 | ((unsigned int)h1 << 16);
        unsigned short l0 = f2bf(v0 - bf2f(h0)), l1 = f2bf(v1 - bf2f(h1));
        *(unsigned int*)&Bl[n * 40 + kk] = l0 | ((unsigned int)l1 << 16);
      }
      __syncthreads();
      const bf16x8 ah  = *(const bf16x8*)&Ah[(w * 16 + r) * 40 + g * 8];
      const bf16x8 al2 = *(const bf16x8*)&Al[(w * 16 + r) * 40 + g * 8];
      #pragma unroll
      for (int nt = 0; nt < 4; ++nt) {
        const bf16x8 bh = *(const bf16x8*)&Bh[(nt * 16 + r) * 40 + g * 8];
        const bf16x8 bl = *(const bf16x8*)&Bl[(nt * 16 + r) * 40 + g * 8];
        acc[nt] = __builtin_amdgcn_mfma_f32_16x16x32_bf16(ah,  bh, acc[nt], 0,0,0);
        acc[nt] = __builtin_amdgcn_mfma_f32_16x16x32_bf16(al2, bh, acc[nt], 0,0,0);
        acc[nt] = __builtin_amdgcn_mfma_f32_16x16x32_bf16(ah,  bl, acc[nt], 0,0,0);
      }
      __syncthreads();
    }
    float* Pout = P0 + (size_t)sk * M * N;
    #pragma unroll
    for (int nt = 0; nt < 4; ++nt) {
      const int cc = col0 + nt * 16 + r;
      if (cc < N) {
        #pragma unroll
        for (int q = 0; q < 4; ++q)
          Pout[(size_t)(row0 + w * 16 + g * 4 + q) * N + cc] = acc[nt][q];
      }
    }
  }
}

// =============== split-K GEMM: P[sk][M][N] = A_chunk @ B_chunk (64x64 tile) ===============
__global__ __launch_bounds__(256) void k_gemm_sk(
    const float* __restrict__ A, const float* __restrict__ B,
    float* __restrict__ P, int M, int K, int N, int kpt)
{
  __shared__ unsigned short Ah[64][40], Al[64][40], Bh[64][40], Bl[64][40];
  const int t = threadIdx.x, lane = t & 63, w = t >> 6, r = lane & 15, g = lane >> 4;
  const int row0 = blockIdx.x * 64, col0 = blockIdx.y * 64;
  const int sk = blockIdx.z;
  const int k0 = sk * kpt * 32;
  const int kend = min(K, k0 + kpt * 32);

  f32x4 acc[4];
  #pragma unroll
  for (int nt = 0; nt < 4; ++nt) acc[nt] = (f32x4){0.f,0.f,0.f,0.f};

  for (int kt = k0; kt < kend; kt += 32) {
    #pragma unroll
    for (int ii = 0; ii < 2; ++ii) {
      const int idx = t + ii * 256, ar = idx >> 3, aq = (idx & 7) * 4, gk = kt + aq;
      const float* ap = &A[(size_t)(row0 + ar) * K + gk];
      float v0 = gk     < kend ? ap[0] : 0.f;
      float v1 = gk + 1 < kend ? ap[1] : 0.f;
      float v2 = gk + 2 < kend ? ap[2] : 0.f;
      float v3 = gk + 3 < kend ? ap[3] : 0.f;
      unsigned short h0=f2bf(v0),h1=f2bf(v1),h2=f2bf(v2),h3=f2bf(v3);
      *(unsigned int*)&Ah[ar][aq]   = h0 | ((unsigned int)h1 << 16);
      *(unsigned int*)&Ah[ar][aq+2] = h2 | ((unsigned int)h3 << 16);
      unsigned short l0=f2bf(v0-bf2f(h0)),l1=f2bf(v1-bf2f(h1)),l2=f2bf(v2-bf2f(h2)),l3=f2bf(v3-bf2f(h3));
      *(unsigned int*)&Al[ar][aq]   = l0 | ((unsigned int)l1 << 16);
      *(unsigned int*)&Al[ar][aq+2] = l2 | ((unsigned int)l3 << 16);
    }
    #pragma unroll
    for (int ii = 0; ii < 4; ++ii) {
      const int idx = t + ii * 256, n = idx & 63, kk = (idx >> 6) * 2;
      const int gn = col0 + n;
      float v0 = (gn < N && kt + kk     < kend) ? B[(size_t)(kt + kk) * N + gn] : 0.f;
      float v1 = (gn < N && kt + kk + 1 < kend) ? B[(size_t)(kt + kk + 1) * N + gn] : 0.f;
      unsigned short h0 = f2bf(v0), h1 = f2bf(v1);
      *(unsigned int*)&Bh[n][kk] = h0 | ((unsigned int)h1 << 16);
      unsigned short l0 = f2bf(v0 - bf2f(h0)), l1 = f2bf(v1 - bf2f(h1));
      *(unsigned int*)&Bl[n][kk] = l0 | ((unsigned int)l1 << 16);
    }
    __syncthreads();
    const bf16x8 ah  = *(const bf16x8*)&Ah[w * 16 + r][g * 8];
    const bf16x8 al2 = *(const bf16x8*)&Al[w * 16 + r][g * 8];
    #pragma unroll
    for (int nt = 0; nt < 4; ++nt) {
      const bf16x8 bh = *(const bf16x8*)&Bh[nt * 16 + r][g * 8];
      const bf16x8 bl = *(const bf16x8*)&Bl[nt * 16 + r][g * 8];
      acc[nt] = __builtin_amdgcn_mfma_f32_16x16x32_bf16(ah,  bh, acc[nt], 0,0,0);
      acc[nt] = __builtin_amdgcn_mfma_f32_16x16x32_bf16(al2, bh, acc[nt], 0,0,0);
      acc[nt] = __builtin_amdgcn_mfma_f32_16x16x32_bf16(ah,  bl, acc[nt], 0,0,0);
    }
    __syncthreads();
  }
  float* Pout = P + (size_t)sk * M * N;
  #pragma unroll
  for (int nt = 0; nt < 4; ++nt) {
    const int cc = col0 + nt * 16 + r;
    if (cc < N) {
      #pragma unroll
      for (int q = 0; q < 4; ++q)
        Pout[(size_t)(row0 + w * 16 + g * 4 + q) * N + cc] = acc[nt][q];
    }
  }
}

// =============== generalized pair: z<nz1 -> problem1 (K1,kpt1), else problem2 (K2,kpt2) ===============
__global__ __launch_bounds__(256) void k_gemm_skp(
    const float* __restrict__ A1, const float* __restrict__ B1, float* __restrict__ P1o,
    int K1, int kpt1, int nz1,
    const float* __restrict__ A2, const float* __restrict__ B2, float* __restrict__ P2o,
    int K2, int kpt2, int M, int N)
{
  __shared__ unsigned short Ah[64][40], Al[64][40], Bh[64][40], Bl[64][40];
  const int t = threadIdx.x, lane = t & 63, w = t >> 6, r = lane & 15, g = lane >> 4;
  const int row0 = blockIdx.x * 64, col0 = blockIdx.y * 64;
  const int zz = blockIdx.z;
  const int second = (zz >= nz1);
  const int sk = second ? zz - nz1 : zz;
  const float* A = second ? A2 : A1;
  const float* B = second ? B2 : B1;
  float* P = second ? P2o : P1o;
  const int K = second ? K2 : K1;
  const int kpt = second ? kpt2 : kpt1;
  const int k0 = sk * kpt * 32;
  const int kend = min(K, k0 + kpt * 32);

  f32x4 acc[4];
  #pragma unroll
  for (int nt = 0; nt < 4; ++nt) acc[nt] = (f32x4){0.f,0.f,0.f,0.f};

  for (int kt = k0; kt < kend; kt += 32) {
    #pragma unroll
    for (int ii = 0; ii < 2; ++ii) {
      const int idx = t + ii * 256, ar = idx >> 3, aq = (idx & 7) * 4, gk = kt + aq;
      const float* ap = &A[(size_t)(row0 + ar) * K + gk];
      float v0 = gk     < kend ? ap[0] : 0.f;
      float v1 = gk + 1 < kend ? ap[1] : 0.f;
      float v2 = gk + 2 < kend ? ap[2] : 0.f;
      float v3 = gk + 3 < kend ? ap[3] : 0.f;
      unsigned short h0=f2bf(v0),h1=f2bf(v1),h2=f2bf(v2),h3=f2bf(v3);
      *(unsigned int*)&Ah[ar][aq]   = h0 | ((unsigned int)h1 << 16);
      *(unsigned int*)&Ah[ar][aq+2] = h2 | ((unsigned int)h3 << 16);
      unsigned short l0=f2bf(v0-bf2f(h0)),l1=f2bf(v1-bf2f(h1)),l2=f2bf(v2-bf2f(h2)),l3=f2bf(v3-bf2f(h3));
      *(unsigned int*)&Al[ar][aq]   = l0 | ((unsigned int)l1 << 16);
      *(unsigned int*)&Al[ar][aq+2] = l2 | ((unsigned int)l3 << 16);
    }
    #pragma unroll
    for (int ii = 0; ii < 4; ++ii) {
      const int idx = t + ii * 256, n = idx & 63, kk = (idx >> 6) * 2;
      const int gn = col0 + n;
      float v0 = (gn < N && kt + kk     < kend) ? B[(size_t)(kt + kk) * N + gn] : 0.f;
      float v1 = (gn < N && kt + kk + 1 < kend) ? B[(size_t)(kt + kk + 1) * N + gn] : 0.f;
      unsigned short h0 = f2bf(v0), h1 = f2bf(v1);
      *(unsigned int*)&Bh[n][kk] = h0 | ((unsigned int)h1 << 16);
      unsigned short l0 = f2bf(v0 - bf2f(h0)), l1 = f2bf(v1 - bf2f(h1));
      *(unsigned int*)&Bl[n][kk] = l0 | ((unsigned int)l1 << 16);
    }
    __syncthreads();
    const bf16x8 ah  = *(const bf16x8*)&Ah[w * 16 + r][g * 8];
    const bf16x8 al2 = *(const bf16x8*)&Al[w * 16 + r][g * 8];
    #pragma unroll
    for (int nt = 0; nt < 4; ++nt) {
      const bf16x8 bh = *(const bf16x8*)&Bh[nt * 16 + r][g * 8];
      const bf16x8 bl = *(const bf16x8*)&Bl[nt * 16 + r][g * 8];
      acc[nt] = __builtin_amdgcn_mfma_f32_16x16x32_bf16(ah,  bh, acc[nt], 0,0,0);
      acc[nt] = __builtin_amdgcn_mfma_f32_16x16x32_bf16(al2, bh, acc[nt], 0,0,0);
      acc[nt] = __builtin_amdgcn_mfma_f32_16x16x32_bf16(ah,  bl, acc[nt], 0,0,0);
    }
    __syncthreads();
  }
  float* Pout = P + (size_t)sk * M * N;
  #pragma unroll
  for (int nt = 0; nt < 4; ++nt) {
    const int cc = col0 + nt * 16 + r;
    if (cc < N) {
      #pragma unroll
      for (int q = 0; q < 4; ++q)
        Pout[(size_t)(row0 + w * 16 + g * 4 + q) * N + cc] = acc[nt][q];
    }
  }
}

// =============== split-K reduce + bias + activation ===============
__global__ __launch_bounds__(256) void k_reduce(
    const float* __restrict__ P, const float* __restrict__ bias,
    float* __restrict__ C, int M, int N, int ldc, int nsk, int act)
{
  const int idx = blockIdx.x * 256 + threadIdx.x;
  if (idx >= M * N) return;
  const int row = idx / N, col = idx - row * N;
  float s = bias[col];
  for (int k = 0; k < nsk; ++k) s += P[(size_t)k * M * N + idx];
  if (act) s = fmaxf(s, 0.f);
  C[(size_t)row * ldc + col] = s;
}

// =============== batched pair reduce: first nblkA blocks -> A, rest -> B ===============
__global__ __launch_bounds__(256) void k_reduce2(
    const float* __restrict__ PA, const float* __restrict__ biasA, float* __restrict__ CA,
    const float* __restrict__ PB, const float* __restrict__ biasB, float* __restrict__ CB,
    int M, int N, int ldc, int nsk, int act, int nblkA)
{
  const int second = (blockIdx.x >= nblkA);
  const float* P = second ? PB : PA;
  const float* bias = second ? biasB : biasA;
  float* C = second ? CB : CA;
  const int idx = (second ? blockIdx.x - nblkA : blockIdx.x) * 256 + threadIdx.x;
  if (idx >= M * N) return;
  const int row = idx / N, col = idx - row * N;
  float s = bias[col];
  for (int k = 0; k < nsk; ++k) s += P[(size_t)k * M * N + idx];
  if (act) s = fmaxf(s, 0.f);
  C[(size_t)row * ldc + col] = s;
}

// =============== final: reduce P4 + bias + relu + GEMV + sigmoid ===============
__global__ __launch_bounds__(512) void k_out(
    const float* __restrict__ P4, const float* __restrict__ f1b,
    const float* __restrict__ w2, const float* __restrict__ b2,
    float* __restrict__ out)
{
  const int t = threadIdx.x, lane = t & 63, w = t >> 6;
  const int b = blockIdx.x * 8 + w;
  float p = 0.f;
  for (int k = lane; k < 300; k += 64) {
    float s = f1b[k];
    #pragma unroll
    for (int s2 = 0; s2 < 4; ++s2)
      s += P4[(size_t)s2 * 512 * 300 + (size_t)b * 300 + k];
    s = fmaxf(s, 0.f);
    p += s * w2[k];
  }
  p = warp_sum(p);
  if (lane == 0) out[b] = 1.f / (1.f + __expf(-(p + b2[0])));
}

extern "C" void kernel_launch(void* const* d_in, const int* in_sizes, int n_in,
                              void* d_out, int out_size, void* d_ws, size_t ws_size,
                              hipStream_t stream)
{
  const float* x    = (const float*)d_in[0];
  const int*   adj  = (const int*)d_in[1];
  const float* fp   = (const float*)d_in[2];
  const float* Whw  = (const float*)d_in[3];
  const float* asrc = (const float*)d_in[4];
  const float* adst = (const float*)d_in[5];
  const float* Wout = (const float*)d_in[6];
  const float* aos  = (const float*)d_in[7];
  const float* aod  = (const float*)d_in[8];
  const float* fc1w = (const float*)d_in[9];
  const float* fc1b = (const float*)d_in[10];
  const float* fc2w = (const float*)d_in[11];
  const float* fc2b = (const float*)d_in[12];
  const float* fcgw = (const float*)d_in[13];
  const float* fcgb = (const float*)d_in[14];
  const float* fcfw = (const float*)d_in[15];
  const float* fcfb = (const float*)d_in[16];
  const float* f1w  = (const float*)d_in[17];
  const float* f1b  = (const float*)d_in[18];
  const float* f2w  = (const float*)d_in[19];
  const float* f2b  = (const float*)d_in[20];
  float* out = (float*)d_out;

  char* wsb = (char*)d_ws;
  unsigned int* buf1 = (unsigned int*)wsb;
  float* s1g = (float*)(wsb + 125829120);
  float* d1g = (float*)(wsb + 127926272);
  float* s2g = (float*)(wsb + 130023424);
  float* d2g = (float*)(wsb + 130285568);
  u64*   mgb = (u64*)  (wsb + 130547712);
  float* gatp = (float*)(wsb + 131596288);
  float* fpnp = (float*)(wsb + 132210688);
  float* f1buf = (float*)(wsb + 132825088);
  float* zb    = (float*)(wsb + 133873664);
  float* z1b   = (float*)(wsb + 135102464);
  float* P0 = (float*)(wsb + 135716864);
  float* P1 = (float*)(wsb + 142008320);
  float* P2 = (float*)(wsb + 144465920);
  float* P3 = (float*)(wsb + 145694720);
  float* P4 = (float*)(wsb + 146923520);
  unsigned short* Bf1H = (unsigned short*)(wsb + 149381120);
  unsigned short* Bf1L = (unsigned short*)(wsb + 149544960);
  unsigned short* Bf2H = (unsigned short*)(wsb + 149708800);
  unsigned short* Bf2L = (unsigned short*)(wsb + 150016000);

  // setup: mask + both weight preps in one launch
  k_setup<<<627, 256, 0, stream>>>(adj, mgb, Whw, Bf1H, Bf1L, Wout, Bf2H, Bf2L);
  // --- GAT chain (unchanged 330 µs baseline) ---
  k_gemm1<<<2048, 512, 0, stream>>>(x, Bf1H, Bf1L, asrc, adst, buf1, s1g, d1g);
  k_att1 <<<4096, 256, 0, stream>>>(buf1, mgb, s1g, d1g);
  k_gemm2<<<1024, 256, 0, stream>>>(buf1, Bf2H, Bf2L, aos, aod, s2g, d2g);
  // att2 batched with independent fc1 GEMM
  k_att2fc1<<<896, 256, 0, stream>>>(buf1, mgb, s2g, d2g, gatp, fp, fc1w, P0);
  // --- head chain ---
  k_reduce<<<1024, 256, 0, stream>>>(P0, fc1b, f1buf, 512, 512, 512, 6, 1);
  // fc2 (z 0..3: f1buf@fc2w->P1, K=512 kpt=4) batched with fcg (z 4..5: gatp@fcgw->P2, K=300 kpt=5)
  k_gemm_skp<<<dim3(8,5,6), 256, 0, stream>>>(f1buf, fc2w, P1, 512, 4, 4,
                                              gatp, fcgw, P2, 300, 5, 512, 300);
  k_reduce<<<600, 256, 0, stream>>>(P1, fc2b, fpnp, 512, 300, 300, 4, 0);
  k_gemm_sk<<<dim3(8,5,2), 256, 0, stream>>>(fpnp, fcfw, P3, 512, 300, 300, 5);
  k_reduce2<<<1200, 256, 0, stream>>>(P2, fcgb, zb, P3, fcfb, zb + 300,
                                      512, 300, 600, 2, 1, 600);
  k_gemm_sk<<<dim3(8,5,4), 256, 0, stream>>>(zb, f1w, P4, 512, 600, 300, 5);
  // out: sigmoid(relu(reduce(P4)+f1b) . w2 + b2)  (reduce folded in; replication-free)
  k_out<<<64, 512, 0, stream>>>(P4, f1b, f2w, f2b, out);
}